// Round 4
// baseline (283.819 us; speedup 1.0000x reference)
//
#include <hip/hip_runtime.h>
#include <cstdint>

// HypHawkes: attn = project(expmap0(softmax((project(expmap0(q))@W.T) @ project(expmap0(ctx)).T / d)))
// R14 = R13 collapsed into ONE persistent kernel (256 blocks x 512 thr, 1 block/CU
//   forced by 128KB LDS -> full co-residency on 256 CUs) with a device-scope sw
//   grid barrier between phases:
//     phase0 prep (q rows + ctx rows + W cvt; 36 chunks/block)
//     phase1 qw GEMM (2 TM=128xTN=64 tiles/block, one per 256-thr half)
//     phase2 sc GEMM (1 256x256 8-phase tile/block; R12 schedule verbatim)
//     phase3 softmax+expmap+project (16 rows/block, 2 at a time)
//   Rationale: per-kernel counters are all at structural reference (sc ~870TF =
//   m248 level, bank-conflict 0; softmax at write floor); residual ~10us is launch
//   gaps + per-kernel L2 flush + cold-dispatch amortization -> fuse and keep the
//   flush explicit (agent-scope release/acquire in the barrier).
//   Barrier: monotonic __device__ counter, target = (old & ~255)+256 -> needs no
//   init, immune to ws poisoning, exact under rocprof replay (each launch +768).
// Accounting model: two 256MiB re-poison fills (~42us each) are a fixed ~84us
//   floor in the timed region; controllable budget ~80us.
// Frozen: R12 sc schedule (8-phase, swizzle, counted vmcnt), R11 qw structure,
//   bf16 intermediate scores, ws overlay.

typedef unsigned short ushort_t;
typedef __bf16 bf16x8 __attribute__((ext_vector_type(8)));
typedef float f32x4 __attribute__((ext_vector_type(4)));

__device__ unsigned g_bar = 0;  // monotonic grid-barrier counter (module .data)

__device__ __forceinline__ unsigned short f32_to_bf16(float f) {
  unsigned int u = __float_as_uint(f);
  u = (u + 0x7fffu + ((u >> 16) & 1u)) >> 16;  // RNE; inputs are finite
  return (unsigned short)u;
}

__device__ __forceinline__ void async_copy16(const void* g, void* s) {
  __builtin_amdgcn_global_load_lds(
      (const __attribute__((address_space(1))) void*)g,
      (__attribute__((address_space(3))) void*)s, 16, 0, 0);
}

// Device-scope grid barrier for EXACTLY 256 co-resident blocks.
// ACQ_REL RMW = L2 writeback (release); ACQUIRE spin load = L2/L1 invalidate.
__device__ __forceinline__ void grid_barrier() {
  __syncthreads();  // drains vmcnt(0): all block stores are in L2 before release
  if (threadIdx.x == 0) {
    unsigned old = __hip_atomic_fetch_add(&g_bar, 1u, __ATOMIC_ACQ_REL,
                                          __HIP_MEMORY_SCOPE_AGENT);
    unsigned tgt = (old & ~255u) + 256u;  // start-of-launch value is ≡0 mod 256
    while (__hip_atomic_load(&g_bar, __ATOMIC_ACQUIRE,
                             __HIP_MEMORY_SCOPE_AGENT) < tgt)
      __builtin_amdgcn_s_sleep(2);
  }
  __syncthreads();
}

#define LDF(base, off) \
  (*reinterpret_cast<const bf16x8*>(reinterpret_cast<const char*>(base) + (off)))

// R12 sc SUBTILE: one 64-K tile, 4 MFMA clusters; mid lgkm0+barrier before
// restaging this buffer; counted vmcnt at tile tail (outside).
#define SUBTILE(BUF, DOSTAGE, K0S)                                                        \
  do {                                                                                    \
    const ushort_t* As_ = &As[BUF][0];                                                    \
    const ushort_t* Bs_ = &Bs[BUF][0];                                                    \
    bf16x8 a0[4], b0[4], a1[4], c0[4], c1[4], b1[4];                                      \
    _Pragma("unroll") for (int mi = 0; mi < 4; ++mi) a0[mi] = LDF(As_, aO0 + mi * 2048);  \
    _Pragma("unroll") for (int ni = 0; ni < 4; ++ni) b0[ni] = LDF(Bs_, bO0 + ni * 2048);  \
    __builtin_amdgcn_s_setprio(1);                                                        \
    _Pragma("unroll") for (int mi = 0; mi < 4; ++mi)                                      \
      _Pragma("unroll") for (int ni = 0; ni < 4; ++ni)                                    \
        acc[mi][ni] = __builtin_amdgcn_mfma_f32_16x16x32_bf16(a0[mi], b0[ni], acc[mi][ni], 0, 0, 0); \
    __builtin_amdgcn_s_setprio(0);                                                        \
    _Pragma("unroll") for (int mi = 0; mi < 4; ++mi) a1[mi] = LDF(As_, aO0 + (4 + mi) * 2048); \
    _Pragma("unroll") for (int mi = 0; mi < 4; ++mi) c0[mi] = LDF(As_, aO1 + mi * 2048);  \
    _Pragma("unroll") for (int mi = 0; mi < 4; ++mi) c1[mi] = LDF(As_, aO1 + (4 + mi) * 2048); \
    _Pragma("unroll") for (int ni = 0; ni < 4; ++ni) b1[ni] = LDF(Bs_, bO1 + ni * 2048);  \
    __builtin_amdgcn_s_setprio(1);                                                        \
    _Pragma("unroll") for (int mi = 0; mi < 4; ++mi)                                      \
      _Pragma("unroll") for (int ni = 0; ni < 4; ++ni)                                    \
        acc[4 + mi][ni] = __builtin_amdgcn_mfma_f32_16x16x32_bf16(a1[mi], b0[ni], acc[4 + mi][ni], 0, 0, 0); \
    __builtin_amdgcn_s_setprio(0);                                                        \
    asm volatile("s_waitcnt lgkmcnt(0)" ::: "memory"); /* all reads of BUF drained */     \
    __builtin_amdgcn_sched_barrier(0);                                                    \
    __builtin_amdgcn_s_barrier();                      /* now safe to overwrite BUF */    \
    if (DOSTAGE) { /* stage A halves of tile t+2 into BUF */                              \
      async_copy16(Ag + (size_t)(K0S), &As[BUF][w * 512]);                                \
      async_copy16(Ag + (size_t)64 * K + (K0S), &As[BUF][4096 + w * 512]);                \
      async_copy16(Ag + (size_t)128 * K + (K0S), &As[BUF][8192 + w * 512]);               \
      async_copy16(Ag + (size_t)192 * K + (K0S), &As[BUF][12288 + w * 512]);              \
    }                                                                                     \
    __builtin_amdgcn_s_setprio(1);                                                        \
    _Pragma("unroll") for (int mi = 0; mi < 4; ++mi)                                      \
      _Pragma("unroll") for (int ni = 0; ni < 4; ++ni)                                    \
        acc[mi][ni] = __builtin_amdgcn_mfma_f32_16x16x32_bf16(c0[mi], b1[ni], acc[mi][ni], 0, 0, 0); \
    __builtin_amdgcn_s_setprio(0);                                                        \
    if (DOSTAGE) { /* stage B halves of tile t+2 into BUF */                              \
      async_copy16(Bg + (size_t)(K0S), &Bs[BUF][w * 512]);                                \
      async_copy16(Bg + (size_t)64 * K + (K0S), &Bs[BUF][4096 + w * 512]);                \
      async_copy16(Bg + (size_t)128 * K + (K0S), &Bs[BUF][8192 + w * 512]);               \
      async_copy16(Bg + (size_t)192 * K + (K0S), &Bs[BUF][12288 + w * 512]);              \
    }                                                                                     \
    __builtin_amdgcn_s_setprio(1);                                                        \
    _Pragma("unroll") for (int mi = 0; mi < 4; ++mi)                                      \
      _Pragma("unroll") for (int ni = 0; ni < 4; ++ni)                                    \
        acc[4 + mi][ni] = __builtin_amdgcn_mfma_f32_16x16x32_bf16(c1[mi], b1[ni], acc[4 + mi][ni], 0, 0, 0); \
    __builtin_amdgcn_s_setprio(0);                                                        \
  } while (0)

__global__ __launch_bounds__(512) void hyp_fused(
    const float* __restrict__ query, const float* __restrict__ ctx,
    const float* __restrict__ W, const float* __restrict__ cptr,
    ushort_t* __restrict__ qn, ushort_t* __restrict__ cn,
    ushort_t* __restrict__ Wb, ushort_t* __restrict__ qw,
    ushort_t* __restrict__ scoresB, float* __restrict__ out,
    int n, int m, int K) {
  __shared__ __align__(16) ushort_t As[2][16384];  // 64 KB
  __shared__ __align__(16) ushort_t Bs[2][16384];  // 64 KB
  __shared__ float redF[16];

  const int b = blockIdx.x;     // 0..255 (grid MUST be 256)
  const int tid = threadIdx.x;  // 0..511
  const int h = tid >> 8;       // half 0/1 (256 threads each)
  const int tidh = tid & 255;
  const int lane = tid & 63;
  const int w = tid >> 6;       // wave 0..7

  const float c = *cptr;
  const float sqrtc = sqrtf(c);
  const float maxn = (1.0f - 4e-3f) / sqrtc;

  // ============ phase 0: prep (q rows / ctx rows / W cvt), 36 chunks ============
  {
    const int total = n + m + (K * K) / 1024;  // 9216
    const int perBlk = total >> 8;             // 36
    for (int it = 0; it < (perBlk >> 1); ++it) {
      const int cku = b * perBlk + it * 2 + h;  // per-half uniform chunk id
      float4 v;
      float ss = 0.f;
      const bool isRow = (cku < n + m);
      if (isRow) {
        const float* x = (cku < n) ? query + (size_t)cku * 1024
                                   : ctx + (size_t)(cku - n) * 1024;
        v = reinterpret_cast<const float4*>(x)[tidh];
        ss = v.x * v.x + v.y * v.y + v.z * v.z + v.w * v.w;
#pragma unroll
        for (int o = 32; o; o >>= 1) ss += __shfl_down(ss, o, 64);
      } else {
        int i = (cku - n - m) * 256 + tidh;
        v = reinterpret_cast<const float4*>(W)[i];
      }
      if (lane == 0) redF[w] = ss;
      __syncthreads();  // every thread passes (uniform trip count both halves)
      if (isRow) {
        float s2 = redF[h * 4] + redF[h * 4 + 1] + redF[h * 4 + 2] + redF[h * 4 + 3];
        const float norm = fmaxf(sqrtf(s2), 1e-5f);
        const float t = tanhf(sqrtc * norm) / (sqrtc * norm);
        const float en = fmaxf(t * norm, 1e-5f);
        const float s = t * (en > maxn ? maxn / en : 1.0f);
        ushort_t* outp = (cku < n) ? qn + (size_t)cku * 1024
                                   : cn + (size_t)(cku - n) * 1024;
        reinterpret_cast<ushort4*>(outp)[tidh] =
            make_ushort4(f32_to_bf16(v.x * s), f32_to_bf16(v.y * s),
                         f32_to_bf16(v.z * s), f32_to_bf16(v.w * s));
      } else {
        int i = (cku - n - m) * 256 + tidh;
        reinterpret_cast<ushort4*>(Wb)[i] =
            make_ushort4(f32_to_bf16(v.x), f32_to_bf16(v.y),
                         f32_to_bf16(v.z), f32_to_bf16(v.w));
      }
      __syncthreads();  // redF WAR protection for next iteration
    }
  }
  grid_barrier();

  // ============ phase 1: qw = qn @ Wb^T (2 tiles/block, one per half) ============
  {
    const int t = 2 * b + h;        // 0..511
    const int gx = t & 31;          // row tile (128)
    const int gy = t >> 5;          // col tile (64)
    const int w4 = (tid >> 6) & 3;  // wave within half
    const int lane15 = lane & 15;
    const int quad = lane >> 4;
    const int wr = w4 >> 1, wc = w4 & 1;
    const size_t rowBase = (size_t)gx * 128;
    const size_t colBase = (size_t)gy * 64;
    const int srow = lane >> 2;
    const int scolE = (lane & 3) * 8;
    const ushort_t* Ag = qn + (rowBase + (size_t)(w4 * 32 + srow)) * K + scolE;
    const ushort_t* Bg = Wb + (colBase + (size_t)(w4 * 16 + srow)) * K + scolE;
    ushort_t* base = &As[0][0] + (size_t)h * 6144;  // 12KB per half
    ushort_t* AsQ = base;                           // 128x32
    ushort_t* BsQ = base + 4096;                    // 64x32
    ushort_t* AsD = AsQ + w4 * 1024;
    ushort_t* BsD = BsQ + w4 * 512;

    f32x4 acc[4][2];
#pragma unroll
    for (int i = 0; i < 4; ++i)
#pragma unroll
      for (int j = 0; j < 2; ++j) acc[i][j] = f32x4{0.f, 0.f, 0.f, 0.f};

    for (int k0 = 0; k0 < K; k0 += 32) {
      async_copy16(Ag + k0, AsD);
      async_copy16(Ag + (size_t)16 * K + k0, AsD + 512);
      async_copy16(Bg + k0, BsD);
      __syncthreads();  // both halves: identical trip count

      bf16x8 af[4], bv[2];
#pragma unroll
      for (int i = 0; i < 4; ++i)
        af[i] = *reinterpret_cast<const bf16x8*>(&AsQ[(wr * 64 + i * 16 + lane15) * 32 + quad * 8]);
#pragma unroll
      for (int j = 0; j < 2; ++j)
        bv[j] = *reinterpret_cast<const bf16x8*>(&BsQ[(wc * 32 + j * 16 + lane15) * 32 + quad * 8]);
#pragma unroll
      for (int i = 0; i < 4; ++i)
#pragma unroll
        for (int j = 0; j < 2; ++j)
          acc[i][j] = __builtin_amdgcn_mfma_f32_16x16x32_bf16(af[i], bv[j], acc[i][j], 0, 0, 0);
      __syncthreads();
    }

#pragma unroll
    for (int i = 0; i < 4; ++i)
#pragma unroll
      for (int j = 0; j < 2; ++j)
#pragma unroll
        for (int r = 0; r < 4; ++r) {
          size_t row = rowBase + (size_t)(wr * 64 + i * 16 + quad * 4 + r);
          size_t col = colBase + (size_t)(wc * 32 + j * 16 + lane15);
          qw[row * K + col] = f32_to_bf16(acc[i][j][r]);
        }
  }
  grid_barrier();

  // ============ phase 2: scoresB = bf16(qw @ cn^T), 256^2 8-phase ============
  {
    const int l15 = lane & 15;
    const int quad = lane >> 4;
    const int wm = w >> 2;
    const int wn = w & 3;
    const size_t rowBase = (size_t)(b & 15) * 256;
    const size_t colBase = (size_t)(b >> 4) * 256;

    const int colsw = (((lane & 7) ^ ((lane >> 3) & 7)) * 8);
    const ushort_t* Ag = qw + (rowBase + (size_t)(w * 8 + (lane >> 3))) * K + colsw;
    const ushort_t* Bg = cn + (colBase + (size_t)(w * 8 + (lane >> 3))) * K + colsw;

    const int axor = (l15 & 7) << 4;
    const int aO0 = (((wm * 128 + l15) * 128) + 0 * 64 + quad * 16) ^ axor;
    const int aO1 = (((wm * 128 + l15) * 128) + 1 * 64 + quad * 16) ^ axor;
    const int bO0 = (((wn * 64 + l15) * 128) + 0 * 64 + quad * 16) ^ axor;
    const int bO1 = (((wn * 64 + l15) * 128) + 1 * 64 + quad * 16) ^ axor;

    f32x4 acc[8][4];
#pragma unroll
    for (int mi = 0; mi < 8; ++mi)
#pragma unroll
      for (int ni = 0; ni < 4; ++ni) acc[mi][ni] = f32x4{0.f, 0.f, 0.f, 0.f};

#pragma unroll
    for (int hk = 0; hk < 4; ++hk)
      async_copy16(Ag + (size_t)(hk * 64) * K, &As[0][hk * 4096 + w * 512]);
#pragma unroll
    for (int hk = 0; hk < 4; ++hk)
      async_copy16(Bg + (size_t)(hk * 64) * K, &Bs[0][hk * 4096 + w * 512]);
#pragma unroll
    for (int hk = 0; hk < 4; ++hk)
      async_copy16(Ag + (size_t)(hk * 64) * K + 64, &As[1][hk * 4096 + w * 512]);
#pragma unroll
    for (int hk = 0; hk < 4; ++hk)
      async_copy16(Bg + (size_t)(hk * 64) * K + 64, &Bs[1][hk * 4096 + w * 512]);
    asm volatile("s_waitcnt vmcnt(8)" ::: "memory");  // tile0 landed (tile1 in flight)
    __builtin_amdgcn_s_barrier();

    for (int i = 0; i < 8; ++i) {
      const bool st = (i < 7);
      const int k0s = i * 128 + 128;
      SUBTILE(0, st, k0s);
      if (st) { asm volatile("s_waitcnt vmcnt(8)" ::: "memory"); }
      else    { asm volatile("s_waitcnt vmcnt(0)" ::: "memory"); }
      __builtin_amdgcn_s_barrier();
      SUBTILE(1, st, k0s + 64);
      if (st) {
        asm volatile("s_waitcnt vmcnt(8)" ::: "memory");
        __builtin_amdgcn_s_barrier();
      }
    }

#pragma unroll
    for (int mi = 0; mi < 8; ++mi)
#pragma unroll
      for (int ni = 0; ni < 4; ++ni)
#pragma unroll
        for (int r = 0; r < 4; ++r) {
          size_t row = rowBase + (size_t)(wm * 128 + mi * 16 + quad * 4 + r);
          size_t col = colBase + (size_t)(wn * 64 + ni * 16 + l15);
          scoresB[row * m + col] = f32_to_bf16(acc[mi][ni][r]);
        }
  }
  grid_barrier();

  // ============ phase 3: softmax + expmap0 + project (16 rows/block) ============
  {
    const float invd = 1.0f / (float)K;
    float* redS = redF;      // [0..8)
    float* redQ = redF + 8;  // [8..16)
    for (int it = 0; it < (n >> 9); ++it) {  // 8 iters, 2 rows (one per half)
      const int row = b * 16 + it * 2 + h;
      const ushort_t* rp = scoresB + (size_t)row * m;
      float* op = out + (size_t)row * m;

      float e[16];
      float sum = 0.f, sq = 0.f;
#pragma unroll
      for (int i = 0; i < 2; ++i) {
        uint4 u = reinterpret_cast<const uint4*>(rp)[i * 256 + tidh];  // 8 bf16
        unsigned int uw[4] = {u.x, u.y, u.z, u.w};
#pragma unroll
        for (int k = 0; k < 4; ++k) {
          float lo = __uint_as_float(uw[k] << 16);
          float hi = __uint_as_float(uw[k] & 0xffff0000u);
          float elo = __expf(lo * invd);
          float ehi = __expf(hi * invd);
          e[i * 8 + k * 2] = elo;
          e[i * 8 + k * 2 + 1] = ehi;
          sum += elo + ehi;
          sq += elo * elo + ehi * ehi;
        }
      }
#pragma unroll
      for (int o = 32; o; o >>= 1) {
        sum += __shfl_down(sum, o, 64);
        sq += __shfl_down(sq, o, 64);
      }
      if (lane == 0) { redS[w] = sum; redQ[w] = sq; }
      __syncthreads();
      sum = redS[h * 4] + redS[h * 4 + 1] + redS[h * 4 + 2] + redS[h * 4 + 3];
      sq = redQ[h * 4] + redQ[h * 4 + 1] + redQ[h * 4 + 2] + redQ[h * 4 + 3];

      const float anorm = sqrtf(sq) / sum;
      const float an = fmaxf(anorm, 1e-5f);
      const float t = tanhf(sqrtc * an) / (sqrtc * an);
      const float pn = fmaxf(t * anorm, 1e-5f);
      const float g = t * (pn > maxn ? maxn / pn : 1.0f) / sum;

#pragma unroll
      for (int i = 0; i < 2; ++i)
#pragma unroll
        for (int k = 0; k < 2; ++k) {
          float4 o = make_float4(e[i * 8 + k * 4] * g, e[i * 8 + k * 4 + 1] * g,
                                 e[i * 8 + k * 4 + 2] * g, e[i * 8 + k * 4 + 3] * g);
          reinterpret_cast<float4*>(op)[(i * 256 + tidh) * 2 + k] = o;
        }
      __syncthreads();  // redS/redQ WAR protection
    }
  }
}

extern "C" void kernel_launch(void* const* d_in, const int* in_sizes, int n_in,
                              void* d_out, int out_size, void* d_ws, size_t ws_size,
                              hipStream_t stream) {
  const float* query = (const float*)d_in[0];
  const float* context = (const float*)d_in[1];
  const float* W = (const float*)d_in[2];
  const float* cptr = (const float*)d_in[3];

  const int d = 1024;
  const int n = in_sizes[0] / d;  // 4096
  const int m = in_sizes[1] / d;  // 4096

  // ws overlay (total 64MB): [cn 16MB][qw 16MB][qn 16MB][Wb 2MB]; after phase1,
  // qn/Wb are dead and scoresB (32MB) reuses bytes [32MB, 64MB).
  ushort_t* cn = (ushort_t*)d_ws;            // m*d bf16
  ushort_t* qw = cn + (size_t)m * d;         // n*d
  ushort_t* qn = qw + (size_t)n * d;         // n*d (dead after phase1)
  ushort_t* Wb = qn + (size_t)n * d;         // d*d (dead after phase1)
  ushort_t* scoresB = qn;                    // n*m bf16, aliases qn+Wb region
  float* attn = (float*)d_out;               // n*m fp32 final output

  // Single persistent launch: grid MUST be exactly 256 (barrier math + residency).
  hyp_fused<<<256, 512, 0, stream>>>(query, context, W, cptr, qn, cn, Wb, qw,
                                     scoresB, attn, n, m, d);
}

// Round 5
// 150.949 us; speedup vs baseline: 1.8802x; 1.8802x over previous
//
#include <hip/hip_runtime.h>
#include <cstdint>

// HypHawkes: attn = project(expmap0(softmax((project(expmap0(q))@W.T) @ project(expmap0(ctx)).T / d)))
// R15 = R13 (R14 persistent-fusion REVERTED: 1-block/CU envelope killed TLP of the
//   memory-bound phases, 165->283us) + gemm_sc switched to MX-fp8:
//   - qw_ctx epilogue stores qw as fp8 e4m3 (4MB); ctx branch stores cn as fp8 (4MB)
//   - gemm_sc: same 256^2 8-phase schedule (barriers/counted-vmcnt identical in
//     shape; 4 loads/tile -> vmcnt(4)), fp8 LDS tiles 256x64B (64KB total),
//     16B-chunk XOR swizzle (chunk ^= (row>>1)&3, both-sides), 8x
//     mfma_scale_f32_32x32x64_f8f6f4 per tile per wave with unit scales
//     (0x7F7F7F7F E8M0 -> 1.0 regardless of op_sel). 2x MFMA rate, half staging
//     and LDS bytes. Scores still written bf16 (softmax path unchanged).
//   Numerics: logits = scores/1024 are ~1e-5..1e-3; softmax shift-invariant; fp8
//   quantization of qw/cn perturbs attn by ~1e-9 << tolerance.
// Accounting model: two 256MiB re-poison fills (~42us each) are a fixed ~84us
//   floor in the timed region; controllable kernel budget ~80us.
// Frozen: R13 prep_q/qw_ctx structure, softmax_hyp, 4-launch pipeline.

typedef unsigned short ushort_t;
typedef __bf16 bf16x8 __attribute__((ext_vector_type(8)));
typedef float f32x4 __attribute__((ext_vector_type(4)));
typedef float f32x16 __attribute__((ext_vector_type(16)));
typedef int i32x4 __attribute__((ext_vector_type(4)));
typedef int i32x8 __attribute__((ext_vector_type(8)));

__device__ __forceinline__ unsigned short f32_to_bf16(float f) {
  unsigned int u = __float_as_uint(f);
  u = (u + 0x7fffu + ((u >> 16) & 1u)) >> 16;  // RNE; inputs are finite
  return (unsigned short)u;
}

__device__ __forceinline__ unsigned char f32_to_fp8(float f) {
  int p = __builtin_amdgcn_cvt_pk_fp8_f32(f, f, 0, false);  // OCP e4m3 on gfx950
  return (unsigned char)(p & 0xFF);
}

__device__ __forceinline__ void async_copy16(const void* g, void* s) {
  __builtin_amdgcn_global_load_lds(
      (const __attribute__((address_space(1))) void*)g,
      (__attribute__((address_space(3))) void*)s, 16, 0, 0);
}

// ---------------- prep_q: q rownorm+expmap+project (bf16), W cvt (bf16) -----
__global__ void prep_q(const float* __restrict__ q, const float* __restrict__ W,
                       ushort_t* __restrict__ qn, ushort_t* __restrict__ Wb,
                       const float* __restrict__ cptr, int n) {
  const int b = blockIdx.x;
  const int tid = threadIdx.x;

  if (b >= n) {  // W conversion chunk
    int i = (b - n) * 256 + tid;
    float4 v = reinterpret_cast<const float4*>(W)[i];
    reinterpret_cast<ushort4*>(Wb)[i] =
        make_ushort4(f32_to_bf16(v.x), f32_to_bf16(v.y), f32_to_bf16(v.z), f32_to_bf16(v.w));
    return;
  }

  const int lane = tid & 63, w = tid >> 6;
  __shared__ float red[4];
  const float* x = q + (size_t)b * 1024;
  ushort_t* out = qn + (size_t)b * 1024;

  float4 v = reinterpret_cast<const float4*>(x)[tid];
  float ss = v.x * v.x + v.y * v.y + v.z * v.z + v.w * v.w;
#pragma unroll
  for (int o = 32; o; o >>= 1) ss += __shfl_down(ss, o, 64);
  if (lane == 0) red[w] = ss;
  __syncthreads();
  ss = red[0] + red[1] + red[2] + red[3];

  const float c = *cptr;
  const float sqrtc = sqrtf(c);
  const float norm = fmaxf(sqrtf(ss), 1e-5f);
  const float t = tanhf(sqrtc * norm) / (sqrtc * norm);
  const float en = fmaxf(t * norm, 1e-5f);
  const float maxn = (1.0f - 4e-3f) / sqrtc;
  const float s = t * (en > maxn ? maxn / en : 1.0f);

  reinterpret_cast<ushort4*>(out)[tid] =
      make_ushort4(f32_to_bf16(v.x * s), f32_to_bf16(v.y * s),
                   f32_to_bf16(v.z * s), f32_to_bf16(v.w * s));
}

// ---------------- qw_ctx: gemm_qw tiles (fp8 out) + ctx prep (fp8 out) ------
__global__ void qw_ctx(const ushort_t* __restrict__ A,
                       const ushort_t* __restrict__ B,
                       unsigned char* __restrict__ Cb,
                       const float* __restrict__ ctx, unsigned char* __restrict__ cn,
                       const float* __restrict__ cptr, int K, int N, int nGemm) {
  __shared__ __align__(16) ushort_t As[128 * 32];
  __shared__ __align__(16) ushort_t Bs[64 * 32];

  const int tid = threadIdx.x;

  if (blockIdx.x >= nGemm) {  // ---------- ctx row prep -> fp8 ----------
    const int r = blockIdx.x - nGemm;
    const int lane = tid & 63, wv = tid >> 6;
    float* red = reinterpret_cast<float*>(As);  // reuse LDS
    const float* x = ctx + (size_t)r * 1024;
    unsigned char* out = cn + (size_t)r * 1024;

    float4 v = reinterpret_cast<const float4*>(x)[tid];
    float ss = v.x * v.x + v.y * v.y + v.z * v.z + v.w * v.w;
#pragma unroll
    for (int o = 32; o; o >>= 1) ss += __shfl_down(ss, o, 64);
    if (lane == 0) red[wv] = ss;
    __syncthreads();
    ss = red[0] + red[1] + red[2] + red[3];

    const float c = *cptr;
    const float sqrtc = sqrtf(c);
    const float norm = fmaxf(sqrtf(ss), 1e-5f);
    const float t = tanhf(sqrtc * norm) / (sqrtc * norm);
    const float en = fmaxf(t * norm, 1e-5f);
    const float maxn = (1.0f - 4e-3f) / sqrtc;
    const float s = t * (en > maxn ? maxn / en : 1.0f);

    int lo = __builtin_amdgcn_cvt_pk_fp8_f32(v.x * s, v.y * s, 0, false);
    int pk = __builtin_amdgcn_cvt_pk_fp8_f32(v.z * s, v.w * s, lo, true);
    reinterpret_cast<int*>(out)[tid] = pk;
    return;
  }

  // ---------- gemm_qw tile (R11 structure; fp8 epilogue) ----------
  const int gx = blockIdx.x & 31;
  const int gy = blockIdx.x >> 5;
  const int w = tid >> 6;
  const int lane = tid & 63;
  const int lane15 = lane & 15;
  const int quad = lane >> 4;
  const int wr = w >> 1, wc = w & 1;

  const size_t rowBase = (size_t)gx * 128;
  const size_t colBase = (size_t)gy * 64;

  const int srow = lane >> 2;
  const int scolE = (lane & 3) * 8;
  const ushort_t* Ag = A + (rowBase + (size_t)(w * 32 + srow)) * K + scolE;
  const ushort_t* Bg = B + (colBase + (size_t)(w * 16 + srow)) * K + scolE;
  ushort_t* AsD = &As[w * 1024];
  ushort_t* BsD = &Bs[w * 512];

  f32x4 acc[4][2];
#pragma unroll
  for (int i = 0; i < 4; ++i)
#pragma unroll
    for (int j = 0; j < 2; ++j) acc[i][j] = f32x4{0.f, 0.f, 0.f, 0.f};

  for (int k0 = 0; k0 < K; k0 += 32) {
    async_copy16(Ag + k0, AsD);
    async_copy16(Ag + (size_t)16 * K + k0, AsD + 512);
    async_copy16(Bg + k0, BsD);
    __syncthreads();

    bf16x8 af[4], bv[2];
#pragma unroll
    for (int i = 0; i < 4; ++i)
      af[i] = *reinterpret_cast<const bf16x8*>(&As[(wr * 64 + i * 16 + lane15) * 32 + quad * 8]);
#pragma unroll
    for (int j = 0; j < 2; ++j)
      bv[j] = *reinterpret_cast<const bf16x8*>(&Bs[(wc * 32 + j * 16 + lane15) * 32 + quad * 8]);
#pragma unroll
    for (int i = 0; i < 4; ++i)
#pragma unroll
      for (int j = 0; j < 2; ++j)
        acc[i][j] = __builtin_amdgcn_mfma_f32_16x16x32_bf16(af[i], bv[j], acc[i][j], 0, 0, 0);
    __syncthreads();
  }

#pragma unroll
  for (int i = 0; i < 4; ++i)
#pragma unroll
    for (int j = 0; j < 2; ++j)
#pragma unroll
      for (int r = 0; r < 4; ++r) {
        size_t row = rowBase + (size_t)(wr * 64 + i * 16 + quad * 4 + r);
        size_t col = colBase + (size_t)(wc * 32 + j * 16 + lane15);
        Cb[row * N + col] = f32_to_fp8(acc[i][j][r]);
      }
}

// ---------------- gemm2: scoresB = bf16(qw8 @ cn8^T), MX-fp8 8-phase --------
// BM=BN=256, BK=64 (one 32x32x64 MFMA-K per tile), 8 waves (2M x 4N), per-wave
// 128x64 out via acc[4][2] of 32x32 tiles. LDS 64KB: As/Bs[2][256*64B] fp8.
// Swizzle (16B-chunk): byte(row,k) at row*64 + ((k>>4)^((row>>1)&3))*16 + (k&15);
// both-sides: staging pre-swizzles the GLOBAL source chunk, reads XOR the chunk.
// Unit scales: 0x7F7F7F7F (E8M0 127 = 1.0 in every byte -> op_sel irrelevant).

#define MFMA8(a, b, c) \
  __builtin_amdgcn_mfma_scale_f32_32x32x64_f8f6f4(a, b, c, 0, 0, 0, 0x7F7F7F7F, 0, 0x7F7F7F7F)

__device__ __forceinline__ i32x8 ld_frag(const unsigned char* p, int off) {
  i32x4 lo = *reinterpret_cast<const i32x4*>(p + off);         // k rel [0,16)
  i32x4 hi = *reinterpret_cast<const i32x4*>(p + (off ^ 16));  // k rel [16,32)
  return __builtin_shufflevector(lo, hi, 0, 1, 2, 3, 4, 5, 6, 7);
}

// One 64-K tile: 12 ds_reads front-loaded, 4 MFMA clusters; mid lgkm0+barrier
// before restaging this buffer; counted vmcnt at tile tail (outside).
#define SUBTILE8(BUF, DOSTAGE, K0S)                                              \
  do {                                                                           \
    const unsigned char* As_ = &As[BUF][0];                                      \
    const unsigned char* Bs_ = &Bs[BUF][0];                                      \
    i32x8 af0 = ld_frag(As_, aO);                                                \
    i32x8 af1 = ld_frag(As_, aO + 2048);                                         \
    i32x8 bf0 = ld_frag(Bs_, bO);                                                \
    i32x8 bf1 = ld_frag(Bs_, bO + 2048);                                         \
    __builtin_amdgcn_s_setprio(1);                                               \
    acc[0][0] = MFMA8(af0, bf0, acc[0][0]);                                      \
    acc[0][1] = MFMA8(af0, bf1, acc[0][1]);                                      \
    acc[1][0] = MFMA8(af1, bf0, acc[1][0]);                                      \
    acc[1][1] = MFMA8(af1, bf1, acc[1][1]);                                      \
    __builtin_amdgcn_s_setprio(0);                                               \
    i32x8 af2 = ld_frag(As_, aO + 2 * 2048);                                     \
    i32x8 af3 = ld_frag(As_, aO + 3 * 2048);                                     \
    __builtin_amdgcn_s_setprio(1);                                               \
    acc[2][0] = MFMA8(af2, bf0, acc[2][0]);                                      \
    acc[2][1] = MFMA8(af2, bf1, acc[2][1]);                                      \
    __builtin_amdgcn_s_setprio(0);                                               \
    asm volatile("s_waitcnt lgkmcnt(0)" ::: "memory"); /* reads of BUF drained */\
    __builtin_amdgcn_sched_barrier(0);                                           \
    __builtin_amdgcn_s_barrier();                      /* safe to overwrite */   \
    if (DOSTAGE) { /* stage A of tile t+2 into BUF */                            \
      async_copy16(Ag + (size_t)(K0S), &As[BUF][w * 1024]);                      \
      async_copy16(Ag + (size_t)128 * K + (K0S), &As[BUF][8192 + w * 1024]);     \
    }                                                                            \
    __builtin_amdgcn_s_setprio(1);                                               \
    acc[3][0] = MFMA8(af3, bf0, acc[3][0]);                                      \
    __builtin_amdgcn_s_setprio(0);                                               \
    if (DOSTAGE) { /* stage B of tile t+2 into BUF */                            \
      async_copy16(Bg + (size_t)(K0S), &Bs[BUF][w * 1024]);                      \
      async_copy16(Bg + (size_t)128 * K + (K0S), &Bs[BUF][8192 + w * 1024]);     \
    }                                                                            \
    __builtin_amdgcn_s_setprio(1);                                               \
    acc[3][1] = MFMA8(af3, bf1, acc[3][1]);                                      \
    __builtin_amdgcn_s_setprio(0);                                               \
  } while (0)

__global__ __launch_bounds__(512) void gemm_sc(const unsigned char* __restrict__ A,
                                               const unsigned char* __restrict__ B,
                                               ushort_t* __restrict__ Sb, int K, int N) {
  __shared__ __align__(16) unsigned char As[2][16384];  // 2 x 256x64B fp8
  __shared__ __align__(16) unsigned char Bs[2][16384];

  const int tid = threadIdx.x;
  const int w = tid >> 6;       // 0..7
  const int lane = tid & 63;
  const int l31 = lane & 31;
  const int wm = w >> 2;        // 0..1 (M half)
  const int wn = w & 3;         // 0..3 (N quarter)

  const size_t rowBase = (size_t)blockIdx.x * 256;
  const size_t colBase = (size_t)blockIdx.y * 256;

  // Staging (linear LDS dest): thread tid covers dest bytes tid*16 of an 8KB
  // round (128 rows); row = tid>>2, dst chunk = tid&3, xr = (row>>1)&3 =
  // (tid>>3)&3 -> src chunk = dst ^ xr. Round 1 adds 128 rows (xr unchanged).
  const int srcC = ((tid & 3) ^ ((tid >> 3) & 3)) * 16;
  const unsigned char* Ag = A + (rowBase + (size_t)(tid >> 2)) * K + srcC;
  const unsigned char* Bg = B + (colBase + (size_t)(tid >> 2)) * K + srcC;

  // Frag-read offsets: lane reads row l31 (+32*mi), k = (lane>>5)*32 + 0..31.
  // xr = ((row)>>1)&3 = ((lane>>1)&3) since mi*32, wm*128, wn*64, ni*32 are ≡0 mod 8.
  const int x2 = (lane >> 1) & 3;
  const int kc0 = (lane >> 5) * 2;
  const int chunkOff = (kc0 ^ x2) * 16;
  const int aO = (wm * 128 + l31) * 64 + chunkOff;  // + mi*2048 (xor-safe, bit11+)
  const int bO = (wn * 64 + l31) * 64 + chunkOff;   // + ni*2048

  f32x16 acc[4][2];
#pragma unroll
  for (int mi = 0; mi < 4; ++mi)
#pragma unroll
    for (int ni = 0; ni < 2; ++ni)
#pragma unroll
      for (int r = 0; r < 16; ++r) acc[mi][ni][r] = 0.f;

  // Prologue: stage tile0 -> buf0 (4 loads), tile1 -> buf1 (4); wait tile0.
  async_copy16(Ag, &As[0][w * 1024]);
  async_copy16(Ag + (size_t)128 * K, &As[0][8192 + w * 1024]);
  async_copy16(Bg, &Bs[0][w * 1024]);
  async_copy16(Bg + (size_t)128 * K, &Bs[0][8192 + w * 1024]);
  async_copy16(Ag + 64, &As[1][w * 1024]);
  async_copy16(Ag + (size_t)128 * K + 64, &As[1][8192 + w * 1024]);
  async_copy16(Bg + 64, &Bs[1][w * 1024]);
  async_copy16(Bg + (size_t)128 * K + 64, &Bs[1][8192 + w * 1024]);
  asm volatile("s_waitcnt vmcnt(4)" ::: "memory");  // tile0 landed (tile1 in flight)
  __builtin_amdgcn_s_barrier();

  // 16 K-tiles (BK=64B), pairs (buf0,buf1). Tile t stages tile t+2.
  for (int i = 0; i < 8; ++i) {
    const bool st = (i < 7);
    const int k0s = i * 128 + 128;  // byte k-offset of tile 2i+2
    SUBTILE8(0, st, k0s);
    if (st) { asm volatile("s_waitcnt vmcnt(4)" ::: "memory"); }  // tile 2i+1 landed
    else    { asm volatile("s_waitcnt vmcnt(0)" ::: "memory"); }  // tile 15 landed
    __builtin_amdgcn_s_barrier();
    SUBTILE8(1, st, k0s + 64);
    if (st) {
      asm volatile("s_waitcnt vmcnt(4)" ::: "memory");            // tile 2i+2 landed
      __builtin_amdgcn_s_barrier();
    }
  }

  // Epilogue: 32x32 C/D layout: col = lane&31, row = (r&3) + 8*(r>>2) + 4*(lane>>5).
  const int rq = lane >> 5;
#pragma unroll
  for (int mi = 0; mi < 4; ++mi)
#pragma unroll
    for (int ni = 0; ni < 2; ++ni)
#pragma unroll
      for (int r = 0; r < 16; ++r) {
        size_t row = rowBase + (size_t)(wm * 128 + mi * 32 + (r & 3) + 8 * (r >> 2) + 4 * rq);
        size_t col = colBase + (size_t)(wn * 64 + ni * 32 + l31);
        Sb[row * N + col] = f32_to_bf16(acc[mi][ni][r]);
      }
}

// ---------------- softmax(row/d) + expmap0 + project: bf16 in, fp32 out ----
__global__ void softmax_hyp(const ushort_t* __restrict__ S, float* __restrict__ out,
                            const float* __restrict__ cptr, float invd) {
  const int tid = threadIdx.x;
  const int lane = tid & 63, w = tid >> 6;
  __shared__ float redS[4], redQ[4];
  const ushort_t* rp = S + (size_t)blockIdx.x * 4096;
  float* op = out + (size_t)blockIdx.x * 4096;

  float e[16];
  float sum = 0.f, sq = 0.f;
#pragma unroll
  for (int i = 0; i < 2; ++i) {
    uint4 u = reinterpret_cast<const uint4*>(rp)[i * 256 + tid];  // 8 bf16
    unsigned int uw[4] = {u.x, u.y, u.z, u.w};
#pragma unroll
    for (int k = 0; k < 4; ++k) {
      float lo = __uint_as_float(uw[k] << 16);
      float hi = __uint_as_float(uw[k] & 0xffff0000u);
      float elo = __expf(lo * invd);
      float ehi = __expf(hi * invd);
      e[i * 8 + k * 2] = elo;
      e[i * 8 + k * 2 + 1] = ehi;
      sum += elo + ehi;
      sq += elo * elo + ehi * ehi;
    }
  }
#pragma unroll
  for (int o = 32; o; o >>= 1) {
    sum += __shfl_down(sum, o, 64);
    sq += __shfl_down(sq, o, 64);
  }
  if (lane == 0) { redS[w] = sum; redQ[w] = sq; }
  __syncthreads();
  sum = redS[0] + redS[1] + redS[2] + redS[3];
  sq = redQ[0] + redQ[1] + redQ[2] + redQ[3];

  const float c = *cptr;
  const float sqrtc = sqrtf(c);
  const float anorm = sqrtf(sq) / sum;
  const float an = fmaxf(anorm, 1e-5f);
  const float t = tanhf(sqrtc * an) / (sqrtc * an);
  const float pn = fmaxf(t * anorm, 1e-5f);
  const float maxn = (1.0f - 4e-3f) / sqrtc;
  const float g = t * (pn > maxn ? maxn / pn : 1.0f) / sum;

#pragma unroll
  for (int i = 0; i < 2; ++i)
#pragma unroll
    for (int k = 0; k < 2; ++k) {
      float4 o = make_float4(e[i * 8 + k * 4] * g, e[i * 8 + k * 4 + 1] * g,
                             e[i * 8 + k * 4 + 2] * g, e[i * 8 + k * 4 + 3] * g);
      reinterpret_cast<float4*>(op)[(i * 256 + tid) * 2 + k] = o;
    }
}

extern "C" void kernel_launch(void* const* d_in, const int* in_sizes, int n_in,
                              void* d_out, int out_size, void* d_ws, size_t ws_size,
                              hipStream_t stream) {
  const float* query = (const float*)d_in[0];
  const float* context = (const float*)d_in[1];
  const float* W = (const float*)d_in[2];
  const float* cptr = (const float*)d_in[3];

  const int d = 1024;
  const int n = in_sizes[0] / d;  // 4096
  const int m = in_sizes[1] / d;  // 4096

  // ws overlay (40MB of 64MB): [cn8 4MB][qw8 4MB][qn 8MB][Wb 2MB]; after qw_ctx,
  // qn/Wb are dead and scoresB (32MB bf16) occupies [8MB, 40MB).
  unsigned char* cn8 = (unsigned char*)d_ws;          // m*d fp8
  unsigned char* qw8 = cn8 + (size_t)m * d;           // n*d fp8
  ushort_t* qn = (ushort_t*)(qw8 + (size_t)n * d);    // n*d bf16 (dead after qw_ctx)
  ushort_t* Wb = qn + (size_t)n * d;                  // d*d bf16 (dead after qw_ctx)
  ushort_t* scoresB = qn;                             // n*m bf16, aliases qn+Wb
  float* attn = (float*)d_out;                        // n*m fp32 final output

  const int nGemm = (n / 128) * (d / 64);             // 512 gemm tiles

  prep_q<<<n + d * d / 1024, 256, 0, stream>>>(query, W, qn, Wb, cptr, n);
  // qw8 = fp8(qn @ Wb^T) overlapped with ctx prep -> cn8
  qw_ctx<<<nGemm + m, 256, 0, stream>>>(qn, Wb, qw8, context, cn8, cptr, d, d, nGemm);
  // scoresB = bf16(qw8 @ cn8^T) : MX-fp8 256^2 8-phase, grid (16,16), 512 thr
  gemm_sc<<<dim3(n / 256, m / 256), 512, 0, stream>>>(qw8, cn8, scoresB, d, m);
  softmax_hyp<<<n, 256, 0, stream>>>(scoresB, attn, cptr, 1.0f / (float)d);
}

// Round 6
// 140.660 us; speedup vs baseline: 2.0178x; 1.0731x over previous
//
#include <hip/hip_runtime.h>
#include <cstdint>

// HypHawkes: attn = project(expmap0(softmax((project(expmap0(q))@W.T) @ project(expmap0(ctx)).T / d)))
// R16 = R15 + GEMM-1 ported to MX-fp8 (same verified recipe as R15's gemm_sc):
//   - prep_q emits qn8/Wb8 directly as fp8 e4m3 (write traffic 10->5MB)
//   - qw_ctx GEMM: TM=128,TN=64,BK=64, 2-barrier loop (16 iters, was 32),
//     3x global_load_lds + 6 ds_read_b128 + 2x mfma_scale_32x32x64 per iter,
//     16B-chunk XOR swizzle both-sides, unit E8M0 scales. ~2x on GEMM part.
//   Numerics: qw was already fp8-quantized in R15; fp8 GEMM-1 inputs grow score
//   error ~sqrt(2)x -> dlogit ~1e-4 -> dattn ~5e-8 << 4.88e-6 threshold.
// Accounting: two 256MiB re-poison fills (~42us each, 80% HBM peak) are a fixed
//   ~84us floor in the timed region; controllable budget ~67us (sc ~26, qw ~13->8,
//   softmax ~13 = its 96MB BW floor, prep ~6, gaps).
// Frozen: R15 gemm_sc (MX-fp8 8-phase, 64KB LDS -> 2 blocks/CU), softmax_hyp,
//   4-launch pipeline (R14 persistent fusion is an anti-pattern: 1-block/CU
//   envelope kills TLP of memory-bound phases).

typedef unsigned short ushort_t;
typedef __bf16 bf16x8 __attribute__((ext_vector_type(8)));
typedef float f32x4 __attribute__((ext_vector_type(4)));
typedef float f32x16 __attribute__((ext_vector_type(16)));
typedef int i32x4 __attribute__((ext_vector_type(4)));
typedef int i32x8 __attribute__((ext_vector_type(8)));

__device__ __forceinline__ unsigned short f32_to_bf16(float f) {
  unsigned int u = __float_as_uint(f);
  u = (u + 0x7fffu + ((u >> 16) & 1u)) >> 16;  // RNE; inputs are finite
  return (unsigned short)u;
}

__device__ __forceinline__ unsigned char f32_to_fp8(float f) {
  int p = __builtin_amdgcn_cvt_pk_fp8_f32(f, f, 0, false);  // OCP e4m3 on gfx950
  return (unsigned char)(p & 0xFF);
}

__device__ __forceinline__ int pack4_fp8(float a, float b, float c, float d) {
  int lo = __builtin_amdgcn_cvt_pk_fp8_f32(a, b, 0, false);
  return __builtin_amdgcn_cvt_pk_fp8_f32(c, d, lo, true);
}

__device__ __forceinline__ void async_copy16(const void* g, void* s) {
  __builtin_amdgcn_global_load_lds(
      (const __attribute__((address_space(1))) void*)g,
      (__attribute__((address_space(3))) void*)s, 16, 0, 0);
}

#define MFMA8(a, b, c) \
  __builtin_amdgcn_mfma_scale_f32_32x32x64_f8f6f4(a, b, c, 0, 0, 0, 0x7F7F7F7F, 0, 0x7F7F7F7F)

// 32B fp8 fragment (K=64 MFMA): lane covers rows (lane&31), k-bytes
// [(lane>>5)*32, +32) = two 16B chunks at off and off^16 (swizzle-adjacent).
__device__ __forceinline__ i32x8 ld_frag(const unsigned char* p, int off) {
  i32x4 lo = *reinterpret_cast<const i32x4*>(p + off);
  i32x4 hi = *reinterpret_cast<const i32x4*>(p + (off ^ 16));
  return __builtin_shufflevector(lo, hi, 0, 1, 2, 3, 4, 5, 6, 7);
}

// ---------------- prep_q: q rownorm+expmap+project -> fp8, W cvt -> fp8 -----
__global__ void prep_q(const float* __restrict__ q, const float* __restrict__ W,
                       unsigned char* __restrict__ qn8, unsigned char* __restrict__ Wb8,
                       const float* __restrict__ cptr, int n) {
  const int b = blockIdx.x;
  const int tid = threadIdx.x;

  if (b >= n) {  // W conversion chunk (1024 floats per block)
    int i = (b - n) * 256 + tid;
    float4 v = reinterpret_cast<const float4*>(W)[i];
    reinterpret_cast<int*>(Wb8)[i] = pack4_fp8(v.x, v.y, v.z, v.w);
    return;
  }

  const int lane = tid & 63, w = tid >> 6;
  __shared__ float red[4];
  const float* x = q + (size_t)b * 1024;
  unsigned char* out = qn8 + (size_t)b * 1024;

  float4 v = reinterpret_cast<const float4*>(x)[tid];
  float ss = v.x * v.x + v.y * v.y + v.z * v.z + v.w * v.w;
#pragma unroll
  for (int o = 32; o; o >>= 1) ss += __shfl_down(ss, o, 64);
  if (lane == 0) red[w] = ss;
  __syncthreads();
  ss = red[0] + red[1] + red[2] + red[3];

  const float c = *cptr;
  const float sqrtc = sqrtf(c);
  const float norm = fmaxf(sqrtf(ss), 1e-5f);
  const float t = tanhf(sqrtc * norm) / (sqrtc * norm);
  const float en = fmaxf(t * norm, 1e-5f);
  const float maxn = (1.0f - 4e-3f) / sqrtc;
  const float s = t * (en > maxn ? maxn / en : 1.0f);

  reinterpret_cast<int*>(out)[tid] = pack4_fp8(v.x * s, v.y * s, v.z * s, v.w * s);
}

// ---------------- qw_ctx: MX-fp8 GEMM-1 tiles + ctx prep (fp8 out) ----------
// blocks [0,nGemm): qw8 = fp8(qn8 @ Wb8^T), TM=128,TN=64,BK=64, 2-barrier loop;
// blocks [nGemm, nGemm+m): ctx row prep -> cn8. Whole-block uniform branch.
__global__ void qw_ctx(const unsigned char* __restrict__ A,
                       const unsigned char* __restrict__ B,
                       unsigned char* __restrict__ Cb,
                       const float* __restrict__ ctx, unsigned char* __restrict__ cn,
                       const float* __restrict__ cptr, int K, int N, int nGemm) {
  __shared__ __align__(16) unsigned char As[128 * 64];  // 8KB
  __shared__ __align__(16) unsigned char Bs[64 * 64];   // 4KB

  const int tid = threadIdx.x;

  if (blockIdx.x >= nGemm) {  // ---------- ctx row prep -> fp8 ----------
    const int r = blockIdx.x - nGemm;
    const int lane = tid & 63, wv = tid >> 6;
    float* red = reinterpret_cast<float*>(As);  // reuse LDS
    const float* x = ctx + (size_t)r * 1024;
    unsigned char* out = cn + (size_t)r * 1024;

    float4 v = reinterpret_cast<const float4*>(x)[tid];
    float ss = v.x * v.x + v.y * v.y + v.z * v.z + v.w * v.w;
#pragma unroll
    for (int o = 32; o; o >>= 1) ss += __shfl_down(ss, o, 64);
    if (lane == 0) red[wv] = ss;
    __syncthreads();
    ss = red[0] + red[1] + red[2] + red[3];

    const float c = *cptr;
    const float sqrtc = sqrtf(c);
    const float norm = fmaxf(sqrtf(ss), 1e-5f);
    const float t = tanhf(sqrtc * norm) / (sqrtc * norm);
    const float en = fmaxf(t * norm, 1e-5f);
    const float maxn = (1.0f - 4e-3f) / sqrtc;
    const float s = t * (en > maxn ? maxn / en : 1.0f);

    reinterpret_cast<int*>(out)[tid] = pack4_fp8(v.x * s, v.y * s, v.z * s, v.w * s);
    return;
  }

  // ---------- GEMM-1 tile: MX-fp8, TM=128 TN=64 BK=64 ----------
  const int gx = blockIdx.x & 31;   // row tile 0..31 (x128)
  const int gy = blockIdx.x >> 5;   // col tile 0..15 (x64)
  const int w = tid >> 6;
  const int lane = tid & 63;
  const int l31 = lane & 31;
  const int wr = w >> 1, wc = w & 1;  // 2x2 wave grid; per-wave out 64x32

  const size_t rowBase = (size_t)gx * 128;
  const size_t colBase = (size_t)gy * 64;

  // Staging (linear LDS dest = tid*16 per 4KB round): row = tid>>2,
  // dst chunk = tid&3, xr = (row>>1)&3 = (tid>>3)&3 -> src chunk = dst ^ xr.
  const int srcC = ((tid & 3) ^ ((tid >> 3) & 3)) * 16;
  const unsigned char* Ag = A + (rowBase + (size_t)(tid >> 2)) * K + srcC;
  const unsigned char* Bg = B + (colBase + (size_t)(tid >> 2)) * K + srcC;

  // Frag-read offsets: row = wr*64 + mi*32 + l31 (xr depends only on l31);
  // k-chunk = (lane>>5)*2 (+1 via ^16 in ld_frag), XOR'd with xr.
  const int x2 = (lane >> 1) & 3;
  const int chunkOff = (((lane >> 5) * 2) ^ x2) * 16;
  const int aO = (wr * 64 + l31) * 64 + chunkOff;  // + mi*2048 (bit11+, xor-safe)
  const int bO = (wc * 32 + l31) * 64 + chunkOff;

  f32x16 acc[2];
#pragma unroll
  for (int mi = 0; mi < 2; ++mi)
#pragma unroll
    for (int r = 0; r < 16; ++r) acc[mi][r] = 0.f;

  for (int k0 = 0; k0 < K; k0 += 64) {
    async_copy16(Ag + k0, &As[w * 1024]);                      // rows 0..63
    async_copy16(Ag + (size_t)64 * K + k0, &As[4096 + w * 1024]);  // rows 64..127
    async_copy16(Bg + k0, &Bs[w * 1024]);                      // rows 0..63
    __syncthreads();  // drains vmcnt+lgkm before reads

    i32x8 a0 = ld_frag(As, aO);
    i32x8 a1 = ld_frag(As, aO + 2048);
    i32x8 b0 = ld_frag(Bs, bO);
    acc[0] = MFMA8(a0, b0, acc[0]);
    acc[1] = MFMA8(a1, b0, acc[1]);
    __syncthreads();
  }

  // Epilogue: 32x32 C/D layout: col = lane&31, row = (r&3)+8*(r>>2)+4*(lane>>5).
  const int rq = lane >> 5;
#pragma unroll
  for (int mi = 0; mi < 2; ++mi)
#pragma unroll
    for (int r = 0; r < 16; ++r) {
      size_t row = rowBase + (size_t)(wr * 64 + mi * 32 + (r & 3) + 8 * (r >> 2) + 4 * rq);
      size_t col = colBase + (size_t)(wc * 32 + l31);
      Cb[row * N + col] = f32_to_fp8(acc[mi][r]);
    }
}

// ---------------- gemm2: scoresB = bf16(qw8 @ cn8^T), MX-fp8 8-phase --------
// R15 verbatim. BM=BN=256, BK=64, 8 waves (2M x 4N), per-wave 128x64 out via
// acc[4][2] of 32x32. LDS 64KB (2 blocks/CU). 16B-chunk XOR swizzle both-sides.

#define SUBTILE8(BUF, DOSTAGE, K0S)                                              \
  do {                                                                           \
    const unsigned char* As_ = &As[BUF][0];                                      \
    const unsigned char* Bs_ = &Bs[BUF][0];                                      \
    i32x8 af0 = ld_frag(As_, aO);                                                \
    i32x8 af1 = ld_frag(As_, aO + 2048);                                         \
    i32x8 bf0 = ld_frag(Bs_, bO);                                                \
    i32x8 bf1 = ld_frag(Bs_, bO + 2048);                                         \
    __builtin_amdgcn_s_setprio(1);                                               \
    acc[0][0] = MFMA8(af0, bf0, acc[0][0]);                                      \
    acc[0][1] = MFMA8(af0, bf1, acc[0][1]);                                      \
    acc[1][0] = MFMA8(af1, bf0, acc[1][0]);                                      \
    acc[1][1] = MFMA8(af1, bf1, acc[1][1]);                                      \
    __builtin_amdgcn_s_setprio(0);                                               \
    i32x8 af2 = ld_frag(As_, aO + 2 * 2048);                                     \
    i32x8 af3 = ld_frag(As_, aO + 3 * 2048);                                     \
    __builtin_amdgcn_s_setprio(1);                                               \
    acc[2][0] = MFMA8(af2, bf0, acc[2][0]);                                      \
    acc[2][1] = MFMA8(af2, bf1, acc[2][1]);                                      \
    __builtin_amdgcn_s_setprio(0);                                               \
    asm volatile("s_waitcnt lgkmcnt(0)" ::: "memory"); /* reads of BUF drained */\
    __builtin_amdgcn_sched_barrier(0);                                           \
    __builtin_amdgcn_s_barrier();                      /* safe to overwrite */   \
    if (DOSTAGE) { /* stage A of tile t+2 into BUF */                            \
      async_copy16(Ag + (size_t)(K0S), &As[BUF][w * 1024]);                      \
      async_copy16(Ag + (size_t)128 * K + (K0S), &As[BUF][8192 + w * 1024]);     \
    }                                                                            \
    __builtin_amdgcn_s_setprio(1);                                               \
    acc[3][0] = MFMA8(af3, bf0, acc[3][0]);                                      \
    __builtin_amdgcn_s_setprio(0);                                               \
    if (DOSTAGE) { /* stage B of tile t+2 into BUF */                            \
      async_copy16(Bg + (size_t)(K0S), &Bs[BUF][w * 1024]);                      \
      async_copy16(Bg + (size_t)128 * K + (K0S), &Bs[BUF][8192 + w * 1024]);     \
    }                                                                            \
    __builtin_amdgcn_s_setprio(1);                                               \
    acc[3][1] = MFMA8(af3, bf1, acc[3][1]);                                      \
    __builtin_amdgcn_s_setprio(0);                                               \
  } while (0)

__global__ __launch_bounds__(512) void gemm_sc(const unsigned char* __restrict__ A,
                                               const unsigned char* __restrict__ B,
                                               ushort_t* __restrict__ Sb, int K, int N) {
  __shared__ __align__(16) unsigned char As[2][16384];  // 2 x 256x64B fp8
  __shared__ __align__(16) unsigned char Bs[2][16384];

  const int tid = threadIdx.x;
  const int w = tid >> 6;       // 0..7
  const int lane = tid & 63;
  const int l31 = lane & 31;
  const int wm = w >> 2;        // 0..1 (M half)
  const int wn = w & 3;         // 0..3 (N quarter)

  const size_t rowBase = (size_t)blockIdx.x * 256;
  const size_t colBase = (size_t)blockIdx.y * 256;

  const int srcC = ((tid & 3) ^ ((tid >> 3) & 3)) * 16;
  const unsigned char* Ag = A + (rowBase + (size_t)(tid >> 2)) * K + srcC;
  const unsigned char* Bg = B + (colBase + (size_t)(tid >> 2)) * K + srcC;

  const int x2 = (lane >> 1) & 3;
  const int kc0 = (lane >> 5) * 2;
  const int chunkOff = (kc0 ^ x2) * 16;
  const int aO = (wm * 128 + l31) * 64 + chunkOff;  // + mi*2048 (xor-safe, bit11+)
  const int bO = (wn * 64 + l31) * 64 + chunkOff;   // + ni*2048

  f32x16 acc[4][2];
#pragma unroll
  for (int mi = 0; mi < 4; ++mi)
#pragma unroll
    for (int ni = 0; ni < 2; ++ni)
#pragma unroll
      for (int r = 0; r < 16; ++r) acc[mi][ni][r] = 0.f;

  // Prologue: stage tile0 -> buf0 (4 loads), tile1 -> buf1 (4); wait tile0.
  async_copy16(Ag, &As[0][w * 1024]);
  async_copy16(Ag + (size_t)128 * K, &As[0][8192 + w * 1024]);
  async_copy16(Bg, &Bs[0][w * 1024]);
  async_copy16(Bg + (size_t)128 * K, &Bs[0][8192 + w * 1024]);
  async_copy16(Ag + 64, &As[1][w * 1024]);
  async_copy16(Ag + (size_t)128 * K + 64, &As[1][8192 + w * 1024]);
  async_copy16(Bg + 64, &Bs[1][w * 1024]);
  async_copy16(Bg + (size_t)128 * K + 64, &Bs[1][8192 + w * 1024]);
  asm volatile("s_waitcnt vmcnt(4)" ::: "memory");  // tile0 landed (tile1 in flight)
  __builtin_amdgcn_s_barrier();

  // 16 K-tiles (BK=64B), pairs (buf0,buf1). Tile t stages tile t+2.
  for (int i = 0; i < 8; ++i) {
    const bool st = (i < 7);
    const int k0s = i * 128 + 128;  // byte k-offset of tile 2i+2
    SUBTILE8(0, st, k0s);
    if (st) { asm volatile("s_waitcnt vmcnt(4)" ::: "memory"); }  // tile 2i+1 landed
    else    { asm volatile("s_waitcnt vmcnt(0)" ::: "memory"); }  // tile 15 landed
    __builtin_amdgcn_s_barrier();
    SUBTILE8(1, st, k0s + 64);
    if (st) {
      asm volatile("s_waitcnt vmcnt(4)" ::: "memory");            // tile 2i+2 landed
      __builtin_amdgcn_s_barrier();
    }
  }

  // Epilogue: 32x32 C/D layout: col = lane&31, row = (r&3) + 8*(r>>2) + 4*(lane>>5).
  const int rq = lane >> 5;
#pragma unroll
  for (int mi = 0; mi < 4; ++mi)
#pragma unroll
    for (int ni = 0; ni < 2; ++ni)
#pragma unroll
      for (int r = 0; r < 16; ++r) {
        size_t row = rowBase + (size_t)(wm * 128 + mi * 32 + (r & 3) + 8 * (r >> 2) + 4 * rq);
        size_t col = colBase + (size_t)(wn * 64 + ni * 32 + l31);
        Sb[row * N + col] = f32_to_bf16(acc[mi][ni][r]);
      }
}

// ---------------- softmax(row/d) + expmap0 + project: bf16 in, fp32 out ----
__global__ void softmax_hyp(const ushort_t* __restrict__ S, float* __restrict__ out,
                            const float* __restrict__ cptr, float invd) {
  const int tid = threadIdx.x;
  const int lane = tid & 63, w = tid >> 6;
  __shared__ float redS[4], redQ[4];
  const ushort_t* rp = S + (size_t)blockIdx.x * 4096;
  float* op = out + (size_t)blockIdx.x * 4096;

  float e[16];
  float sum = 0.f, sq = 0.f;
#pragma unroll
  for (int i = 0; i < 2; ++i) {
    uint4 u = reinterpret_cast<const uint4*>(rp)[i * 256 + tid];  // 8 bf16
    unsigned int uw[4] = {u.x, u.y, u.z, u.w};
#pragma unroll
    for (int k = 0; k < 4; ++k) {
      float lo = __uint_as_float(uw[k] << 16);
      float hi = __uint_as_float(uw[k] & 0xffff0000u);
      float elo = __expf(lo * invd);
      float ehi = __expf(hi * invd);
      e[i * 8 + k * 2] = elo;
      e[i * 8 + k * 2 + 1] = ehi;
      sum += elo + ehi;
      sq += elo * elo + ehi * ehi;
    }
  }
#pragma unroll
  for (int o = 32; o; o >>= 1) {
    sum += __shfl_down(sum, o, 64);
    sq += __shfl_down(sq, o, 64);
  }
  if (lane == 0) { redS[w] = sum; redQ[w] = sq; }
  __syncthreads();
  sum = redS[0] + redS[1] + redS[2] + redS[3];
  sq = redQ[0] + redQ[1] + redQ[2] + redQ[3];

  const float c = *cptr;
  const float sqrtc = sqrtf(c);
  const float anorm = sqrtf(sq) / sum;
  const float an = fmaxf(anorm, 1e-5f);
  const float t = tanhf(sqrtc * an) / (sqrtc * an);
  const float pn = fmaxf(t * anorm, 1e-5f);
  const float maxn = (1.0f - 4e-3f) / sqrtc;
  const float g = t * (pn > maxn ? maxn / pn : 1.0f) / sum;

#pragma unroll
  for (int i = 0; i < 2; ++i)
#pragma unroll
    for (int k = 0; k < 2; ++k) {
      float4 o = make_float4(e[i * 8 + k * 4] * g, e[i * 8 + k * 4 + 1] * g,
                             e[i * 8 + k * 4 + 2] * g, e[i * 8 + k * 4 + 3] * g);
      reinterpret_cast<float4*>(op)[(i * 256 + tid) * 2 + k] = o;
    }
}

extern "C" void kernel_launch(void* const* d_in, const int* in_sizes, int n_in,
                              void* d_out, int out_size, void* d_ws, size_t ws_size,
                              hipStream_t stream) {
  const float* query = (const float*)d_in[0];
  const float* context = (const float*)d_in[1];
  const float* W = (const float*)d_in[2];
  const float* cptr = (const float*)d_in[3];

  const int d = 1024;
  const int n = in_sizes[0] / d;  // 4096
  const int m = in_sizes[1] / d;  // 4096

  // ws overlay (45MB of 64MB, all disjoint):
  // [cn8 4MB][qw8 4MB][qn8 4MB][Wb8 1MB][scoresB 32MB]
  unsigned char* cn8 = (unsigned char*)d_ws;          // m*d fp8
  unsigned char* qw8 = cn8 + (size_t)m * d;           // n*d fp8
  unsigned char* qn8 = qw8 + (size_t)n * d;           // n*d fp8
  unsigned char* Wb8 = qn8 + (size_t)n * d;           // d*d fp8
  ushort_t* scoresB = (ushort_t*)(Wb8 + (size_t)d * d);  // n*m bf16
  float* attn = (float*)d_out;                        // n*m fp32 final output

  const int nGemm = (n / 128) * (d / 64);             // 512 gemm tiles

  prep_q<<<n + d * d / 1024, 256, 0, stream>>>(query, W, qn8, Wb8, cptr, n);
  // qw8 = fp8(qn8 @ Wb8^T) (MX-fp8 tiles) overlapped with ctx prep -> cn8
  qw_ctx<<<nGemm + m, 256, 0, stream>>>(qn8, Wb8, qw8, context, cn8, cptr, d, d, nGemm);
  // scoresB = bf16(qw8 @ cn8^T) : MX-fp8 256^2 8-phase, grid (16,16), 512 thr
  gemm_sc<<<dim3(n / 256, m / 256), 512, 0, stream>>>(qw8, cn8, scoresB, d, m);
  softmax_hyp<<<n, 256, 0, stream>>>(scoresB, attn, cptr, 1.0f / (float)d);
}

// Round 7
// 133.923 us; speedup vs baseline: 2.1193x; 1.0503x over previous
//
#include <hip/hip_runtime.h>
#include <cstdint>

// HypHawkes: attn = project(expmap0(softmax((project(expmap0(q))@W.T) @ project(expmap0(ctx)).T / d)))
// R17 = R16 + fp8 intermediate scores:
//   - gemm_sc epilogue stores scores as fp8 e4m3 (32->16MB write)
//   - softmax_hyp reads fp8 scores (32->16MB read), decodes via v_cvt_pk_f32_fp8,
//     lane-interleaved per quarter-row so reads AND float4 writes stay coalesced.
//   Numerics: logits = scores/1024; |scores| ~ 0.15 (dots of unit-norm 1024-d
//   vectors) -> fp8 abs err <~1e-2 -> dlogit <~1e-5 -> dattn ~2e-9 << 4.88e-6.
// Accounting: two 256MiB re-poison fills (~42us each, ~80% HBM peak) are a fixed
//   ~84us floor; controllable ~57us (sc ~26, softmax ~13->11, qw_ctx ~8, prep ~5).
// Frozen: R16 MX-fp8 GEMM recipe both GEMMs (32x32x64 f8f6f4, unit E8M0 scales,
//   16B-chunk XOR swizzle both-sides), R15 8-phase sc schedule, 4-launch pipeline
//   (R14 persistent fusion = anti-pattern: 1-block/CU envelope kills TLP).

typedef unsigned short ushort_t;
typedef float f32x2 __attribute__((ext_vector_type(2)));
typedef float f32x4 __attribute__((ext_vector_type(4)));
typedef float f32x16 __attribute__((ext_vector_type(16)));
typedef int i32x4 __attribute__((ext_vector_type(4)));
typedef int i32x8 __attribute__((ext_vector_type(8)));

__device__ __forceinline__ unsigned char f32_to_fp8(float f) {
  int p = __builtin_amdgcn_cvt_pk_fp8_f32(f, f, 0, false);  // OCP e4m3 on gfx950
  return (unsigned char)(p & 0xFF);
}

__device__ __forceinline__ int pack4_fp8(float a, float b, float c, float d) {
  int lo = __builtin_amdgcn_cvt_pk_fp8_f32(a, b, 0, false);
  return __builtin_amdgcn_cvt_pk_fp8_f32(c, d, lo, true);
}

__device__ __forceinline__ void async_copy16(const void* g, void* s) {
  __builtin_amdgcn_global_load_lds(
      (const __attribute__((address_space(1))) void*)g,
      (__attribute__((address_space(3))) void*)s, 16, 0, 0);
}

#define MFMA8(a, b, c) \
  __builtin_amdgcn_mfma_scale_f32_32x32x64_f8f6f4(a, b, c, 0, 0, 0, 0x7F7F7F7F, 0, 0x7F7F7F7F)

// 32B fp8 fragment (K=64 MFMA): lane covers rows (lane&31), k-bytes
// [(lane>>5)*32, +32) = two 16B chunks at off and off^16 (swizzle-adjacent).
__device__ __forceinline__ i32x8 ld_frag(const unsigned char* p, int off) {
  i32x4 lo = *reinterpret_cast<const i32x4*>(p + off);
  i32x4 hi = *reinterpret_cast<const i32x4*>(p + (off ^ 16));
  return __builtin_shufflevector(lo, hi, 0, 1, 2, 3, 4, 5, 6, 7);
}

// ---------------- prep_q: q rownorm+expmap+project -> fp8, W cvt -> fp8 -----
__global__ void prep_q(const float* __restrict__ q, const float* __restrict__ W,
                       unsigned char* __restrict__ qn8, unsigned char* __restrict__ Wb8,
                       const float* __restrict__ cptr, int n) {
  const int b = blockIdx.x;
  const int tid = threadIdx.x;

  if (b >= n) {  // W conversion chunk (1024 floats per block)
    int i = (b - n) * 256 + tid;
    float4 v = reinterpret_cast<const float4*>(W)[i];
    reinterpret_cast<int*>(Wb8)[i] = pack4_fp8(v.x, v.y, v.z, v.w);
    return;
  }

  const int lane = tid & 63, w = tid >> 6;
  __shared__ float red[4];
  const float* x = q + (size_t)b * 1024;
  unsigned char* out = qn8 + (size_t)b * 1024;

  float4 v = reinterpret_cast<const float4*>(x)[tid];
  float ss = v.x * v.x + v.y * v.y + v.z * v.z + v.w * v.w;
#pragma unroll
  for (int o = 32; o; o >>= 1) ss += __shfl_down(ss, o, 64);
  if (lane == 0) red[w] = ss;
  __syncthreads();
  ss = red[0] + red[1] + red[2] + red[3];

  const float c = *cptr;
  const float sqrtc = sqrtf(c);
  const float norm = fmaxf(sqrtf(ss), 1e-5f);
  const float t = tanhf(sqrtc * norm) / (sqrtc * norm);
  const float en = fmaxf(t * norm, 1e-5f);
  const float maxn = (1.0f - 4e-3f) / sqrtc;
  const float s = t * (en > maxn ? maxn / en : 1.0f);

  reinterpret_cast<int*>(out)[tid] = pack4_fp8(v.x * s, v.y * s, v.z * s, v.w * s);
}

// ---------------- qw_ctx: MX-fp8 GEMM-1 tiles + ctx prep (fp8 out) ----------
// blocks [0,nGemm): qw8 = fp8(qn8 @ Wb8^T), TM=128,TN=64,BK=64, 2-barrier loop;
// blocks [nGemm, nGemm+m): ctx row prep -> cn8. Whole-block uniform branch.
__global__ void qw_ctx(const unsigned char* __restrict__ A,
                       const unsigned char* __restrict__ B,
                       unsigned char* __restrict__ Cb,
                       const float* __restrict__ ctx, unsigned char* __restrict__ cn,
                       const float* __restrict__ cptr, int K, int N, int nGemm) {
  __shared__ __align__(16) unsigned char As[128 * 64];  // 8KB
  __shared__ __align__(16) unsigned char Bs[64 * 64];   // 4KB

  const int tid = threadIdx.x;

  if (blockIdx.x >= nGemm) {  // ---------- ctx row prep -> fp8 ----------
    const int r = blockIdx.x - nGemm;
    const int lane = tid & 63, wv = tid >> 6;
    float* red = reinterpret_cast<float*>(As);  // reuse LDS
    const float* x = ctx + (size_t)r * 1024;
    unsigned char* out = cn + (size_t)r * 1024;

    float4 v = reinterpret_cast<const float4*>(x)[tid];
    float ss = v.x * v.x + v.y * v.y + v.z * v.z + v.w * v.w;
#pragma unroll
    for (int o = 32; o; o >>= 1) ss += __shfl_down(ss, o, 64);
    if (lane == 0) red[wv] = ss;
    __syncthreads();
    ss = red[0] + red[1] + red[2] + red[3];

    const float c = *cptr;
    const float sqrtc = sqrtf(c);
    const float norm = fmaxf(sqrtf(ss), 1e-5f);
    const float t = tanhf(sqrtc * norm) / (sqrtc * norm);
    const float en = fmaxf(t * norm, 1e-5f);
    const float maxn = (1.0f - 4e-3f) / sqrtc;
    const float s = t * (en > maxn ? maxn / en : 1.0f);

    reinterpret_cast<int*>(out)[tid] = pack4_fp8(v.x * s, v.y * s, v.z * s, v.w * s);
    return;
  }

  // ---------- GEMM-1 tile: MX-fp8, TM=128 TN=64 BK=64 ----------
  const int gx = blockIdx.x & 31;   // row tile 0..31 (x128)
  const int gy = blockIdx.x >> 5;   // col tile 0..15 (x64)
  const int w = tid >> 6;
  const int lane = tid & 63;
  const int l31 = lane & 31;
  const int wr = w >> 1, wc = w & 1;  // 2x2 wave grid; per-wave out 64x32

  const size_t rowBase = (size_t)gx * 128;
  const size_t colBase = (size_t)gy * 64;

  // Staging (linear LDS dest = tid*16 per 4KB round): row = tid>>2,
  // dst chunk = tid&3, xr = (row>>1)&3 = (tid>>3)&3 -> src chunk = dst ^ xr.
  const int srcC = ((tid & 3) ^ ((tid >> 3) & 3)) * 16;
  const unsigned char* Ag = A + (rowBase + (size_t)(tid >> 2)) * K + srcC;
  const unsigned char* Bg = B + (colBase + (size_t)(tid >> 2)) * K + srcC;

  // Frag-read offsets: row = wr*64 + mi*32 + l31 (xr depends only on l31);
  // k-chunk = (lane>>5)*2 (+1 via ^16 in ld_frag), XOR'd with xr.
  const int x2 = (lane >> 1) & 3;
  const int chunkOff = (((lane >> 5) * 2) ^ x2) * 16;
  const int aO = (wr * 64 + l31) * 64 + chunkOff;  // + mi*2048 (bit11+, xor-safe)
  const int bO = (wc * 32 + l31) * 64 + chunkOff;

  f32x16 acc[2];
#pragma unroll
  for (int mi = 0; mi < 2; ++mi)
#pragma unroll
    for (int r = 0; r < 16; ++r) acc[mi][r] = 0.f;

  for (int k0 = 0; k0 < K; k0 += 64) {
    async_copy16(Ag + k0, &As[w * 1024]);                          // rows 0..63
    async_copy16(Ag + (size_t)64 * K + k0, &As[4096 + w * 1024]);  // rows 64..127
    async_copy16(Bg + k0, &Bs[w * 1024]);                          // rows 0..63
    __syncthreads();  // drains vmcnt+lgkm before reads

    i32x8 a0 = ld_frag(As, aO);
    i32x8 a1 = ld_frag(As, aO + 2048);
    i32x8 b0 = ld_frag(Bs, bO);
    acc[0] = MFMA8(a0, b0, acc[0]);
    acc[1] = MFMA8(a1, b0, acc[1]);
    __syncthreads();
  }

  // Epilogue: 32x32 C/D layout: col = lane&31, row = (r&3)+8*(r>>2)+4*(lane>>5).
  const int rq = lane >> 5;
#pragma unroll
  for (int mi = 0; mi < 2; ++mi)
#pragma unroll
    for (int r = 0; r < 16; ++r) {
      size_t row = rowBase + (size_t)(wr * 64 + mi * 32 + (r & 3) + 8 * (r >> 2) + 4 * rq);
      size_t col = colBase + (size_t)(wc * 32 + l31);
      Cb[row * N + col] = f32_to_fp8(acc[mi][r]);
    }
}

// ---------------- gemm2: scores8 = fp8(qw8 @ cn8^T), MX-fp8 8-phase ---------
// BM=BN=256, BK=64, 8 waves (2M x 4N), per-wave 128x64 out via acc[4][2] of
// 32x32. LDS 64KB. 16B-chunk XOR swizzle both-sides. fp8 score stores (R17).

#define SUBTILE8(BUF, DOSTAGE, K0S)                                              \
  do {                                                                           \
    const unsigned char* As_ = &As[BUF][0];                                      \
    const unsigned char* Bs_ = &Bs[BUF][0];                                      \
    i32x8 af0 = ld_frag(As_, aO);                                                \
    i32x8 af1 = ld_frag(As_, aO + 2048);                                         \
    i32x8 bf0 = ld_frag(Bs_, bO);                                                \
    i32x8 bf1 = ld_frag(Bs_, bO + 2048);                                         \
    __builtin_amdgcn_s_setprio(1);                                               \
    acc[0][0] = MFMA8(af0, bf0, acc[0][0]);                                      \
    acc[0][1] = MFMA8(af0, bf1, acc[0][1]);                                      \
    acc[1][0] = MFMA8(af1, bf0, acc[1][0]);                                      \
    acc[1][1] = MFMA8(af1, bf1, acc[1][1]);                                      \
    __builtin_amdgcn_s_setprio(0);                                               \
    i32x8 af2 = ld_frag(As_, aO + 2 * 2048);                                     \
    i32x8 af3 = ld_frag(As_, aO + 3 * 2048);                                     \
    __builtin_amdgcn_s_setprio(1);                                               \
    acc[2][0] = MFMA8(af2, bf0, acc[2][0]);                                      \
    acc[2][1] = MFMA8(af2, bf1, acc[2][1]);                                      \
    __builtin_amdgcn_s_setprio(0);                                               \
    asm volatile("s_waitcnt lgkmcnt(0)" ::: "memory"); /* reads of BUF drained */\
    __builtin_amdgcn_sched_barrier(0);                                           \
    __builtin_amdgcn_s_barrier();                      /* safe to overwrite */   \
    if (DOSTAGE) { /* stage A of tile t+2 into BUF */                            \
      async_copy16(Ag + (size_t)(K0S), &As[BUF][w * 1024]);                      \
      async_copy16(Ag + (size_t)128 * K + (K0S), &As[BUF][8192 + w * 1024]);     \
    }                                                                            \
    __builtin_amdgcn_s_setprio(1);                                               \
    acc[3][0] = MFMA8(af3, bf0, acc[3][0]);                                      \
    __builtin_amdgcn_s_setprio(0);                                               \
    if (DOSTAGE) { /* stage B of tile t+2 into BUF */                            \
      async_copy16(Bg + (size_t)(K0S), &Bs[BUF][w * 1024]);                      \
      async_copy16(Bg + (size_t)128 * K + (K0S), &Bs[BUF][8192 + w * 1024]);     \
    }                                                                            \
    __builtin_amdgcn_s_setprio(1);                                               \
    acc[3][1] = MFMA8(af3, bf1, acc[3][1]);                                      \
    __builtin_amdgcn_s_setprio(0);                                               \
  } while (0)

__global__ __launch_bounds__(512) void gemm_sc(const unsigned char* __restrict__ A,
                                               const unsigned char* __restrict__ B,
                                               unsigned char* __restrict__ Sb, int K, int N) {
  __shared__ __align__(16) unsigned char As[2][16384];  // 2 x 256x64B fp8
  __shared__ __align__(16) unsigned char Bs[2][16384];

  const int tid = threadIdx.x;
  const int w = tid >> 6;       // 0..7
  const int lane = tid & 63;
  const int l31 = lane & 31;
  const int wm = w >> 2;        // 0..1 (M half)
  const int wn = w & 3;         // 0..3 (N quarter)

  const size_t rowBase = (size_t)blockIdx.x * 256;
  const size_t colBase = (size_t)blockIdx.y * 256;

  const int srcC = ((tid & 3) ^ ((tid >> 3) & 3)) * 16;
  const unsigned char* Ag = A + (rowBase + (size_t)(tid >> 2)) * K + srcC;
  const unsigned char* Bg = B + (colBase + (size_t)(tid >> 2)) * K + srcC;

  const int x2 = (lane >> 1) & 3;
  const int kc0 = (lane >> 5) * 2;
  const int chunkOff = (kc0 ^ x2) * 16;
  const int aO = (wm * 128 + l31) * 64 + chunkOff;  // + mi*2048 (xor-safe, bit11+)
  const int bO = (wn * 64 + l31) * 64 + chunkOff;   // + ni*2048

  f32x16 acc[4][2];
#pragma unroll
  for (int mi = 0; mi < 4; ++mi)
#pragma unroll
    for (int ni = 0; ni < 2; ++ni)
#pragma unroll
      for (int r = 0; r < 16; ++r) acc[mi][ni][r] = 0.f;

  // Prologue: stage tile0 -> buf0 (4 loads), tile1 -> buf1 (4); wait tile0.
  async_copy16(Ag, &As[0][w * 1024]);
  async_copy16(Ag + (size_t)128 * K, &As[0][8192 + w * 1024]);
  async_copy16(Bg, &Bs[0][w * 1024]);
  async_copy16(Bg + (size_t)128 * K, &Bs[0][8192 + w * 1024]);
  async_copy16(Ag + 64, &As[1][w * 1024]);
  async_copy16(Ag + (size_t)128 * K + 64, &As[1][8192 + w * 1024]);
  async_copy16(Bg + 64, &Bs[1][w * 1024]);
  async_copy16(Bg + (size_t)128 * K + 64, &Bs[1][8192 + w * 1024]);
  asm volatile("s_waitcnt vmcnt(4)" ::: "memory");  // tile0 landed (tile1 in flight)
  __builtin_amdgcn_s_barrier();

  // 16 K-tiles (BK=64B), pairs (buf0,buf1). Tile t stages tile t+2.
  for (int i = 0; i < 8; ++i) {
    const bool st = (i < 7);
    const int k0s = i * 128 + 128;  // byte k-offset of tile 2i+2
    SUBTILE8(0, st, k0s);
    if (st) { asm volatile("s_waitcnt vmcnt(4)" ::: "memory"); }  // tile 2i+1 landed
    else    { asm volatile("s_waitcnt vmcnt(0)" ::: "memory"); }  // tile 15 landed
    __builtin_amdgcn_s_barrier();
    SUBTILE8(1, st, k0s + 64);
    if (st) {
      asm volatile("s_waitcnt vmcnt(4)" ::: "memory");            // tile 2i+2 landed
      __builtin_amdgcn_s_barrier();
    }
  }

  // Epilogue: 32x32 C/D layout: col = lane&31, row = (r&3) + 8*(r>>2) + 4*(lane>>5).
  const int rq = lane >> 5;
#pragma unroll
  for (int mi = 0; mi < 4; ++mi)
#pragma unroll
    for (int ni = 0; ni < 2; ++ni)
#pragma unroll
      for (int r = 0; r < 16; ++r) {
        size_t row = rowBase + (size_t)(wm * 128 + mi * 32 + (r & 3) + 8 * (r >> 2) + 4 * rq);
        size_t col = colBase + (size_t)(wn * 64 + ni * 32 + l31);
        Sb[row * N + col] = f32_to_fp8(acc[mi][ni][r]);
      }
}

// ---------------- softmax(row/d) + expmap0 + project: fp8 in, fp32 out ------
// No max pass: logits = scores/1024 are ~+/-2e-4; exp cannot overflow.
// Lane-interleaved quarters: read uint (4 fp8) at [k*256+tid], write float4 at
// [k*256+tid] -> both coalesced, e-values stay in the producing thread.
__global__ void softmax_hyp(const unsigned char* __restrict__ S, float* __restrict__ out,
                            const float* __restrict__ cptr, float invd) {
  const int tid = threadIdx.x;
  const int lane = tid & 63, w = tid >> 6;
  __shared__ float redS[4], redQ[4];
  const unsigned char* rp = S + (size_t)blockIdx.x * 4096;
  float* op = out + (size_t)blockIdx.x * 4096;

  float e[16];
  float sum = 0.f, sq = 0.f;
#pragma unroll
  for (int k = 0; k < 4; ++k) {
    unsigned uw = reinterpret_cast<const unsigned*>(rp)[k * 256 + tid];  // 4 fp8
    f32x2 lo = __builtin_amdgcn_cvt_pk_f32_fp8(uw, false);
    f32x2 hi = __builtin_amdgcn_cvt_pk_f32_fp8(uw, true);
    float e0 = __expf(lo[0] * invd);
    float e1 = __expf(lo[1] * invd);
    float e2 = __expf(hi[0] * invd);
    float e3 = __expf(hi[1] * invd);
    e[k * 4 + 0] = e0; e[k * 4 + 1] = e1; e[k * 4 + 2] = e2; e[k * 4 + 3] = e3;
    sum += e0 + e1 + e2 + e3;
    sq += e0 * e0 + e1 * e1 + e2 * e2 + e3 * e3;
  }
#pragma unroll
  for (int o = 32; o; o >>= 1) {
    sum += __shfl_down(sum, o, 64);
    sq += __shfl_down(sq, o, 64);
  }
  if (lane == 0) { redS[w] = sum; redQ[w] = sq; }
  __syncthreads();
  sum = redS[0] + redS[1] + redS[2] + redS[3];
  sq = redQ[0] + redQ[1] + redQ[2] + redQ[3];

  const float c = *cptr;
  const float sqrtc = sqrtf(c);
  const float anorm = sqrtf(sq) / sum;       // |attn|
  const float an = fmaxf(anorm, 1e-5f);      // expmap0 clamp
  const float t = tanhf(sqrtc * an) / (sqrtc * an);
  const float pn = fmaxf(t * anorm, 1e-5f);  // |expmap0(attn)| (project clamp)
  const float maxn = (1.0f - 4e-3f) / sqrtc;
  const float g = t * (pn > maxn ? maxn / pn : 1.0f) / sum;

#pragma unroll
  for (int k = 0; k < 4; ++k) {
    float4 o = make_float4(e[k * 4] * g, e[k * 4 + 1] * g,
                           e[k * 4 + 2] * g, e[k * 4 + 3] * g);
    reinterpret_cast<float4*>(op)[k * 256 + tid] = o;
  }
}

extern "C" void kernel_launch(void* const* d_in, const int* in_sizes, int n_in,
                              void* d_out, int out_size, void* d_ws, size_t ws_size,
                              hipStream_t stream) {
  const float* query = (const float*)d_in[0];
  const float* context = (const float*)d_in[1];
  const float* W = (const float*)d_in[2];
  const float* cptr = (const float*)d_in[3];

  const int d = 1024;
  const int n = in_sizes[0] / d;  // 4096
  const int m = in_sizes[1] / d;  // 4096

  // ws overlay (29MB of 64MB, all disjoint):
  // [cn8 4MB][qw8 4MB][qn8 4MB][Wb8 1MB][scores8 16MB]
  unsigned char* cn8 = (unsigned char*)d_ws;             // m*d fp8
  unsigned char* qw8 = cn8 + (size_t)m * d;              // n*d fp8
  unsigned char* qn8 = qw8 + (size_t)n * d;              // n*d fp8
  unsigned char* Wb8 = qn8 + (size_t)n * d;              // d*d fp8
  unsigned char* scores8 = Wb8 + (size_t)d * d;          // n*m fp8
  float* attn = (float*)d_out;                           // n*m fp32 final output

  const int nGemm = (n / 128) * (d / 64);                // 512 gemm tiles

  prep_q<<<n + d * d / 1024, 256, 0, stream>>>(query, W, qn8, Wb8, cptr, n);
  // qw8 = fp8(qn8 @ Wb8^T) (MX-fp8 tiles) overlapped with ctx prep -> cn8
  qw_ctx<<<nGemm + m, 256, 0, stream>>>(qn8, Wb8, qw8, context, cn8, cptr, d, d, nGemm);
  // scores8 = fp8(qw8 @ cn8^T) : MX-fp8 256^2 8-phase, grid (16,16), 512 thr
  gemm_sc<<<dim3(n / 256, m / 256), 512, 0, stream>>>(qw8, cn8, scores8, d, m);
  softmax_hyp<<<n, 256, 0, stream>>>(scores8, attn, cptr, 1.0f / (float)d);
}

// Round 9
// 133.717 us; speedup vs baseline: 2.1225x; 1.0015x over previous
//
#include <hip/hip_runtime.h>
#include <cstdint>

// HypHawkes: attn = project(expmap0(softmax((project(expmap0(q))@W.T) @ project(expmap0(ctx)).T / d)))
// R18b = R18 resubmitted byte-identical (R8-round bench was an infra failure:
//   "container failed twice", no kernel verdict; audit found no hang/fault risk).
// R18 = R17 + gemm_sc split for cross-block overlap: BM=128 x BN=256, grid
//   (32,16)=512 blocks = 2 blocks/CU (was 256 blocks = 1/CU). At 1 block/CU every
//   barrier stalled the whole CU (gemm_sc ~22us vs ~7us MFMA / ~8us LDS floors);
//   with 2 co-resident blocks one block's barrier/vmcnt stalls overlap the other's
//   compute (R14's lesson applied in reverse). LDS 48KB; __launch_bounds__(512,4)
//   pins VGPR<=128 so 16 waves/CU fit. Per-wave 64x64 out: acc[2][2] f32x16,
//   4 MFMA + 8 ds_read_b128 + 3 staged loads per K-tile, counted vmcnt(3).
//   Same verified MX-fp8 recipe (32x32x64 f8f6f4 unit-scale, 16B-chunk XOR
//   swizzle both-sides, 2-cluster subtile with mid lgkm0+barrier).
// Accounting: two 256MiB re-poison fills (~42us, ~80% HBM peak) = fixed ~84us
//   floor; controllable ~50us (sc ~22->14, softmax ~11 = 64MB-write floor,
//   qw_ctx ~8, prep ~5, gaps ~4).
// Frozen: R17 fp8 scores + softmax, R16 GEMM-1/prep, 4-launch pipeline
//   (R14 persistent fusion = anti-pattern).

typedef unsigned short ushort_t;
typedef float f32x2 __attribute__((ext_vector_type(2)));
typedef float f32x4 __attribute__((ext_vector_type(4)));
typedef float f32x16 __attribute__((ext_vector_type(16)));
typedef int i32x4 __attribute__((ext_vector_type(4)));
typedef int i32x8 __attribute__((ext_vector_type(8)));

__device__ __forceinline__ unsigned char f32_to_fp8(float f) {
  int p = __builtin_amdgcn_cvt_pk_fp8_f32(f, f, 0, false);  // OCP e4m3 on gfx950
  return (unsigned char)(p & 0xFF);
}

__device__ __forceinline__ int pack4_fp8(float a, float b, float c, float d) {
  int lo = __builtin_amdgcn_cvt_pk_fp8_f32(a, b, 0, false);
  return __builtin_amdgcn_cvt_pk_fp8_f32(c, d, lo, true);
}

__device__ __forceinline__ void async_copy16(const void* g, void* s) {
  __builtin_amdgcn_global_load_lds(
      (const __attribute__((address_space(1))) void*)g,
      (__attribute__((address_space(3))) void*)s, 16, 0, 0);
}

#define MFMA8(a, b, c) \
  __builtin_amdgcn_mfma_scale_f32_32x32x64_f8f6f4(a, b, c, 0, 0, 0, 0x7F7F7F7F, 0, 0x7F7F7F7F)

// 32B fp8 fragment (K=64 MFMA): lane covers rows (lane&31), k-bytes
// [(lane>>5)*32, +32) = two 16B chunks at off and off^16 (swizzle-adjacent).
__device__ __forceinline__ i32x8 ld_frag(const unsigned char* p, int off) {
  i32x4 lo = *reinterpret_cast<const i32x4*>(p + off);
  i32x4 hi = *reinterpret_cast<const i32x4*>(p + (off ^ 16));
  return __builtin_shufflevector(lo, hi, 0, 1, 2, 3, 4, 5, 6, 7);
}

// ---------------- prep_q: q rownorm+expmap+project -> fp8, W cvt -> fp8 -----
__global__ void prep_q(const float* __restrict__ q, const float* __restrict__ W,
                       unsigned char* __restrict__ qn8, unsigned char* __restrict__ Wb8,
                       const float* __restrict__ cptr, int n) {
  const int b = blockIdx.x;
  const int tid = threadIdx.x;

  if (b >= n) {  // W conversion chunk (1024 floats per block)
    int i = (b - n) * 256 + tid;
    float4 v = reinterpret_cast<const float4*>(W)[i];
    reinterpret_cast<int*>(Wb8)[i] = pack4_fp8(v.x, v.y, v.z, v.w);
    return;
  }

  const int lane = tid & 63, w = tid >> 6;
  __shared__ float red[4];
  const float* x = q + (size_t)b * 1024;
  unsigned char* out = qn8 + (size_t)b * 1024;

  float4 v = reinterpret_cast<const float4*>(x)[tid];
  float ss = v.x * v.x + v.y * v.y + v.z * v.z + v.w * v.w;
#pragma unroll
  for (int o = 32; o; o >>= 1) ss += __shfl_down(ss, o, 64);
  if (lane == 0) red[w] = ss;
  __syncthreads();
  ss = red[0] + red[1] + red[2] + red[3];

  const float c = *cptr;
  const float sqrtc = sqrtf(c);
  const float norm = fmaxf(sqrtf(ss), 1e-5f);
  const float t = tanhf(sqrtc * norm) / (sqrtc * norm);
  const float en = fmaxf(t * norm, 1e-5f);
  const float maxn = (1.0f - 4e-3f) / sqrtc;
  const float s = t * (en > maxn ? maxn / en : 1.0f);

  reinterpret_cast<int*>(out)[tid] = pack4_fp8(v.x * s, v.y * s, v.z * s, v.w * s);
}

// ---------------- qw_ctx: MX-fp8 GEMM-1 tiles + ctx prep (fp8 out) ----------
// blocks [0,nGemm): qw8 = fp8(qn8 @ Wb8^T), TM=128,TN=64,BK=64, 2-barrier loop;
// blocks [nGemm, nGemm+m): ctx row prep -> cn8. Whole-block uniform branch.
__global__ void qw_ctx(const unsigned char* __restrict__ A,
                       const unsigned char* __restrict__ B,
                       unsigned char* __restrict__ Cb,
                       const float* __restrict__ ctx, unsigned char* __restrict__ cn,
                       const float* __restrict__ cptr, int K, int N, int nGemm) {
  __shared__ __align__(16) unsigned char As[128 * 64];  // 8KB
  __shared__ __align__(16) unsigned char Bs[64 * 64];   // 4KB

  const int tid = threadIdx.x;

  if (blockIdx.x >= nGemm) {  // ---------- ctx row prep -> fp8 ----------
    const int r = blockIdx.x - nGemm;
    const int lane = tid & 63, wv = tid >> 6;
    float* red = reinterpret_cast<float*>(As);  // reuse LDS
    const float* x = ctx + (size_t)r * 1024;
    unsigned char* out = cn + (size_t)r * 1024;

    float4 v = reinterpret_cast<const float4*>(x)[tid];
    float ss = v.x * v.x + v.y * v.y + v.z * v.z + v.w * v.w;
#pragma unroll
    for (int o = 32; o; o >>= 1) ss += __shfl_down(ss, o, 64);
    if (lane == 0) red[wv] = ss;
    __syncthreads();
    ss = red[0] + red[1] + red[2] + red[3];

    const float c = *cptr;
    const float sqrtc = sqrtf(c);
    const float norm = fmaxf(sqrtf(ss), 1e-5f);
    const float t = tanhf(sqrtc * norm) / (sqrtc * norm);
    const float en = fmaxf(t * norm, 1e-5f);
    const float maxn = (1.0f - 4e-3f) / sqrtc;
    const float s = t * (en > maxn ? maxn / en : 1.0f);

    reinterpret_cast<int*>(out)[tid] = pack4_fp8(v.x * s, v.y * s, v.z * s, v.w * s);
    return;
  }

  // ---------- GEMM-1 tile: MX-fp8, TM=128 TN=64 BK=64 ----------
  const int gx = blockIdx.x & 31;   // row tile 0..31 (x128)
  const int gy = blockIdx.x >> 5;   // col tile 0..15 (x64)
  const int w = tid >> 6;
  const int lane = tid & 63;
  const int l31 = lane & 31;
  const int wr = w >> 1, wc = w & 1;  // 2x2 wave grid; per-wave out 64x32

  const size_t rowBase = (size_t)gx * 128;
  const size_t colBase = (size_t)gy * 64;

  // Staging (linear LDS dest = tid*16 per 4KB round): row = tid>>2,
  // dst chunk = tid&3, xr = (row>>1)&3 = (tid>>3)&3 -> src chunk = dst ^ xr.
  const int srcC = ((tid & 3) ^ ((tid >> 3) & 3)) * 16;
  const unsigned char* Ag = A + (rowBase + (size_t)(tid >> 2)) * K + srcC;
  const unsigned char* Bg = B + (colBase + (size_t)(tid >> 2)) * K + srcC;

  // Frag-read offsets: row = wr*64 + mi*32 + l31 (xr depends only on l31);
  // k-chunk = (lane>>5)*2 (+1 via ^16 in ld_frag), XOR'd with xr.
  const int x2 = (lane >> 1) & 3;
  const int chunkOff = (((lane >> 5) * 2) ^ x2) * 16;
  const int aO = (wr * 64 + l31) * 64 + chunkOff;  // + mi*2048 (bit11+, xor-safe)
  const int bO = (wc * 32 + l31) * 64 + chunkOff;

  f32x16 acc[2];
#pragma unroll
  for (int mi = 0; mi < 2; ++mi)
#pragma unroll
    for (int r = 0; r < 16; ++r) acc[mi][r] = 0.f;

  for (int k0 = 0; k0 < K; k0 += 64) {
    async_copy16(Ag + k0, &As[w * 1024]);                          // rows 0..63
    async_copy16(Ag + (size_t)64 * K + k0, &As[4096 + w * 1024]);  // rows 64..127
    async_copy16(Bg + k0, &Bs[w * 1024]);                          // rows 0..63
    __syncthreads();  // drains vmcnt+lgkm before reads

    i32x8 a0 = ld_frag(As, aO);
    i32x8 a1 = ld_frag(As, aO + 2048);
    i32x8 b0 = ld_frag(Bs, bO);
    acc[0] = MFMA8(a0, b0, acc[0]);
    acc[1] = MFMA8(a1, b0, acc[1]);
    __syncthreads();
  }

  // Epilogue: 32x32 C/D layout: col = lane&31, row = (r&3)+8*(r>>2)+4*(lane>>5).
  const int rq = lane >> 5;
#pragma unroll
  for (int mi = 0; mi < 2; ++mi)
#pragma unroll
    for (int r = 0; r < 16; ++r) {
      size_t row = rowBase + (size_t)(wr * 64 + mi * 32 + (r & 3) + 8 * (r >> 2) + 4 * rq);
      size_t col = colBase + (size_t)(wc * 32 + l31);
      Cb[row * N + col] = f32_to_fp8(acc[mi][r]);
    }
}

// ---------------- gemm2: scores8 = fp8(qw8 @ cn8^T), MX-fp8, 2 blocks/CU ----
// R18: BM=128, BN=256, BK=64, grid (32,16)=512 blocks (2/CU). 8 waves (2M x 4N),
// per-wave 64x64 out = acc[2][2] of 32x32. LDS 48KB: As[2][128x64B]+Bs[2][256x64B].
// 16B-chunk XOR swizzle both-sides. Counted vmcnt(3): 3 loads/tile, 2 in flight.

#define SUBTILE2(BUF, DOSTAGE, K0S)                                              \
  do {                                                                           \
    const unsigned char* As_ = &As[BUF][0];                                      \
    const unsigned char* Bs_ = &Bs[BUF][0];                                      \
    i32x8 a0 = ld_frag(As_, aO);                                                 \
    i32x8 a1 = ld_frag(As_, aO + 2048);                                          \
    i32x8 b0 = ld_frag(Bs_, bO);                                                 \
    i32x8 b1 = ld_frag(Bs_, bO + 2048);                                          \
    __builtin_amdgcn_s_setprio(1);                                               \
    acc[0][0] = MFMA8(a0, b0, acc[0][0]);                                        \
    acc[0][1] = MFMA8(a0, b1, acc[0][1]);                                        \
    __builtin_amdgcn_s_setprio(0);                                               \
    asm volatile("s_waitcnt lgkmcnt(0)" ::: "memory"); /* reads of BUF drained */\
    __builtin_amdgcn_sched_barrier(0);                                           \
    __builtin_amdgcn_s_barrier();                      /* safe to overwrite */   \
    if (DOSTAGE) { /* stage tile t+2 into BUF: A 1 round, B 2 rounds */          \
      async_copy16(Ag + (size_t)(K0S), &As[BUF][w * 1024]);                      \
      async_copy16(Bg + (size_t)(K0S), &Bs[BUF][w * 1024]);                      \
      async_copy16(Bg + (size_t)128 * K + (K0S), &Bs[BUF][8192 + w * 1024]);     \
    }                                                                            \
    __builtin_amdgcn_s_setprio(1);                                               \
    acc[1][0] = MFMA8(a1, b0, acc[1][0]);                                        \
    acc[1][1] = MFMA8(a1, b1, acc[1][1]);                                        \
    __builtin_amdgcn_s_setprio(0);                                               \
  } while (0)

__global__ __launch_bounds__(512, 4) void gemm_sc(const unsigned char* __restrict__ A,
                                                  const unsigned char* __restrict__ B,
                                                  unsigned char* __restrict__ Sb,
                                                  int K, int N) {
  __shared__ __align__(16) unsigned char As[2][8192];   // 2 x 128x64B fp8
  __shared__ __align__(16) unsigned char Bs[2][16384];  // 2 x 256x64B fp8

  const int tid = threadIdx.x;
  const int w = tid >> 6;       // 0..7
  const int lane = tid & 63;
  const int l31 = lane & 31;
  const int wm = w >> 2;        // 0..1 (M half, 64 rows each)
  const int wn = w & 3;         // 0..3 (N quarter, 64 cols each)

  const size_t rowBase = (size_t)blockIdx.x * 128;
  const size_t colBase = (size_t)blockIdx.y * 256;

  // Staging: 512 thr x 16B = 8KB/round. row = tid>>2, dst chunk = tid&3,
  // xr = (row>>1)&3 = (tid>>3)&3 -> src chunk = dst ^ xr. +128 rows keeps xr.
  const int srcC = ((tid & 3) ^ ((tid >> 3) & 3)) * 16;
  const unsigned char* Ag = A + (rowBase + (size_t)(tid >> 2)) * K + srcC;
  const unsigned char* Bg = B + (colBase + (size_t)(tid >> 2)) * K + srcC;

  // Frag-read offsets (swizzled): row = wm*64 (+mi*32) + l31 for A,
  // wn*64 (+ni*32) + l31 for B; xr depends only on l31 (32-multiples drop out).
  const int x2 = (lane >> 1) & 3;
  const int chunkOff = (((lane >> 5) * 2) ^ x2) * 16;
  const int aO = (wm * 64 + l31) * 64 + chunkOff;  // + mi*2048 (bit11+, xor-safe)
  const int bO = (wn * 64 + l31) * 64 + chunkOff;  // + ni*2048

  f32x16 acc[2][2];
#pragma unroll
  for (int mi = 0; mi < 2; ++mi)
#pragma unroll
    for (int ni = 0; ni < 2; ++ni)
#pragma unroll
      for (int r = 0; r < 16; ++r) acc[mi][ni][r] = 0.f;

  // Prologue: stage tile0 -> buf0 (3 loads), tile1 -> buf1 (3); wait tile0.
  async_copy16(Ag, &As[0][w * 1024]);
  async_copy16(Bg, &Bs[0][w * 1024]);
  async_copy16(Bg + (size_t)128 * K, &Bs[0][8192 + w * 1024]);
  async_copy16(Ag + 64, &As[1][w * 1024]);
  async_copy16(Bg + 64, &Bs[1][w * 1024]);
  async_copy16(Bg + (size_t)128 * K + 64, &Bs[1][8192 + w * 1024]);
  asm volatile("s_waitcnt vmcnt(3)" ::: "memory");  // tile0 landed (tile1 in flight)
  __builtin_amdgcn_s_barrier();

  // 16 K-tiles (BK=64B), pairs (buf0,buf1). Tile t stages tile t+2.
  for (int i = 0; i < 8; ++i) {
    const bool st = (i < 7);
    const int k0s = i * 128 + 128;  // byte k-offset of tile 2i+2
    SUBTILE2(0, st, k0s);
    if (st) { asm volatile("s_waitcnt vmcnt(3)" ::: "memory"); }  // tile 2i+1 landed
    else    { asm volatile("s_waitcnt vmcnt(0)" ::: "memory"); }  // tile 15 landed
    __builtin_amdgcn_s_barrier();
    SUBTILE2(1, st, k0s + 64);
    if (st) {
      asm volatile("s_waitcnt vmcnt(3)" ::: "memory");            // tile 2i+2 landed
      __builtin_amdgcn_s_barrier();
    }
  }

  // Epilogue: 32x32 C/D layout: col = lane&31, row = (r&3)+8*(r>>2)+4*(lane>>5).
  const int rq = lane >> 5;
#pragma unroll
  for (int mi = 0; mi < 2; ++mi)
#pragma unroll
    for (int ni = 0; ni < 2; ++ni)
#pragma unroll
      for (int r = 0; r < 16; ++r) {
        size_t row = rowBase + (size_t)(wm * 64 + mi * 32 + (r & 3) + 8 * (r >> 2) + 4 * rq);
        size_t col = colBase + (size_t)(wn * 64 + ni * 32 + l31);
        Sb[row * N + col] = f32_to_fp8(acc[mi][ni][r]);
      }
}

// ---------------- softmax(row/d) + expmap0 + project: fp8 in, fp32 out ------
// No max pass: logits = scores/1024 are ~+/-2e-4; exp cannot overflow.
// Lane-interleaved quarters: read uint (4 fp8) at [k*256+tid], write float4 at
// [k*256+tid] -> both coalesced, e-values stay in the producing thread.
__global__ void softmax_hyp(const unsigned char* __restrict__ S, float* __restrict__ out,
                            const float* __restrict__ cptr, float invd) {
  const int tid = threadIdx.x;
  const int lane = tid & 63, w = tid >> 6;
  __shared__ float redS[4], redQ[4];
  const unsigned char* rp = S + (size_t)blockIdx.x * 4096;
  float* op = out + (size_t)blockIdx.x * 4096;

  float e[16];
  float sum = 0.f, sq = 0.f;
#pragma unroll
  for (int k = 0; k < 4; ++k) {
    unsigned uw = reinterpret_cast<const unsigned*>(rp)[k * 256 + tid];  // 4 fp8
    f32x2 lo = __builtin_amdgcn_cvt_pk_f32_fp8(uw, false);
    f32x2 hi = __builtin_amdgcn_cvt_pk_f32_fp8(uw, true);
    float e0 = __expf(lo[0] * invd);
    float e1 = __expf(lo[1] * invd);
    float e2 = __expf(hi[0] * invd);
    float e3 = __expf(hi[1] * invd);
    e[k * 4 + 0] = e0; e[k * 4 + 1] = e1; e[k * 4 + 2] = e2; e[k * 4 + 3] = e3;
    sum += e0 + e1 + e2 + e3;
    sq += e0 * e0 + e1 * e1 + e2 * e2 + e3 * e3;
  }
#pragma unroll
  for (int o = 32; o; o >>= 1) {
    sum += __shfl_down(sum, o, 64);
    sq += __shfl_down(sq, o, 64);
  }
  if (lane == 0) { redS[w] = sum; redQ[w] = sq; }
  __syncthreads();
  sum = redS[0] + redS[1] + redS[2] + redS[3];
  sq = redQ[0] + redQ[1] + redQ[2] + redQ[3];

  const float c = *cptr;
  const float sqrtc = sqrtf(c);
  const float anorm = sqrtf(sq) / sum;       // |attn|
  const float an = fmaxf(anorm, 1e-5f);      // expmap0 clamp
  const float t = tanhf(sqrtc * an) / (sqrtc * an);
  const float pn = fmaxf(t * anorm, 1e-5f);  // |expmap0(attn)| (project clamp)
  const float maxn = (1.0f - 4e-3f) / sqrtc;
  const float g = t * (pn > maxn ? maxn / pn : 1.0f) / sum;

#pragma unroll
  for (int k = 0; k < 4; ++k) {
    float4 o = make_float4(e[k * 4] * g, e[k * 4 + 1] * g,
                           e[k * 4 + 2] * g, e[k * 4 + 3] * g);
    reinterpret_cast<float4*>(op)[k * 256 + tid] = o;
  }
}

extern "C" void kernel_launch(void* const* d_in, const int* in_sizes, int n_in,
                              void* d_out, int out_size, void* d_ws, size_t ws_size,
                              hipStream_t stream) {
  const float* query = (const float*)d_in[0];
  const float* context = (const float*)d_in[1];
  const float* W = (const float*)d_in[2];
  const float* cptr = (const float*)d_in[3];

  const int d = 1024;
  const int n = in_sizes[0] / d;  // 4096
  const int m = in_sizes[1] / d;  // 4096

  // ws overlay (29MB of 64MB, all disjoint):
  // [cn8 4MB][qw8 4MB][qn8 4MB][Wb8 1MB][scores8 16MB]
  unsigned char* cn8 = (unsigned char*)d_ws;             // m*d fp8
  unsigned char* qw8 = cn8 + (size_t)m * d;              // n*d fp8
  unsigned char* qn8 = qw8 + (size_t)n * d;              // n*d fp8
  unsigned char* Wb8 = qn8 + (size_t)n * d;              // d*d fp8
  unsigned char* scores8 = Wb8 + (size_t)d * d;          // n*m fp8
  float* attn = (float*)d_out;                           // n*m fp32 final output

  const int nGemm = (n / 128) * (d / 64);                // 512 gemm tiles

  prep_q<<<n + d * d / 1024, 256, 0, stream>>>(query, W, qn8, Wb8, cptr, n);
  // qw8 = fp8(qn8 @ Wb8^T) (MX-fp8 tiles) overlapped with ctx prep -> cn8
  qw_ctx<<<nGemm + m, 256, 0, stream>>>(qn8, Wb8, qw8, context, cn8, cptr, d, d, nGemm);
  // scores8 = fp8(qw8 @ cn8^T) : MX-fp8, BM=128 BN=256, grid (32,16), 2 blk/CU
  gemm_sc<<<dim3(n / 128, m / 256), 512, 0, stream>>>(qw8, cn8, scores8, d, m);
  softmax_hyp<<<n, 256, 0, stream>>>(scores8, attn, cptr, 1.0f / (float)d);
}